// Round 12
// baseline (478.583 us; speedup 1.0000x reference)
//
#include <hip/hip_runtime.h>
#include <stdint.h>

typedef __attribute__((ext_vector_type(8))) short bf16x8;
typedef __attribute__((ext_vector_type(4))) float f32x4;

__device__ __forceinline__ float b2f(short s) {
  union { unsigned u; float f; } a; a.u = ((unsigned)(unsigned short)s) << 16; return a.f;
}
__device__ __forceinline__ short f2b(float f) {
  union { float f; unsigned u; } a; a.f = f;
  unsigned r = a.u + 0x7fffu + ((a.u >> 16) & 1u);
  return (short)(r >> 16);
}
__device__ __forceinline__ void gload16(const void* g, void* l) {
  __builtin_amdgcn_global_load_lds((__attribute__((address_space(1))) void*)g,
                                   (__attribute__((address_space(3))) void*)l, 16, 0, 0);
}

// LDS XOR swizzle (T2, rule-21 form)
#define SWZ(row, col) ((col) ^ (((row) & 7) << 3))

// ---------------- SF fused permute + transpose + inv-norm (+rowsum zero) ----------------
// block = (c, b): stages x-plane permuted to bf16 in LDS (48 rows x 1280, pitch 1288),
// writes Q row-panel, QT col-panel, row inv-norms; zeros its rowsum slice.
__global__ __launch_bounds__(256) void permute_sf2_k(const float* __restrict__ x,
                                                     short* __restrict__ Q,
                                                     short* __restrict__ QT,
                                                     float* __restrict__ inv,
                                                     float* __restrict__ rowsum) {
  __shared__ short kw[48 * 1288];
  __shared__ float ssrow[48];
  int tid = threadIdx.x;
  int c = blockIdx.x, b = blockIdx.y;
  int bid = b * 64 + c;
  if (tid < 48) { rowsum[bid * 48 + tid] = 0.f; ssrow[tid] = 0.f; }
  for (int e = tid; e < 48 * 88; e += 256) {
    int r = e / 88, q = e - r * 88;
    kw[r * 1288 + 1200 + q] = 0;
  }
  const float* xp = x + ((long)(b * 64 + c)) * 57600;
  for (int i = 0; i < 225; ++i) {
    int e = tid + 256 * i;
    int uv = e / 2304, r2 = e - uv * 2304;
    int hh = r2 / 48, w = r2 - hh * 48;
    kw[hh * 1288 + w * 25 + uv] = f2b(xp[e]);
  }
  __syncthreads();
  // Q rows (coalesced) + per-row sumsq
  long qb = ((long)b * 3072 + c * 48) * 1280;
  for (int ci2 = tid; ci2 < 7680; ci2 += 256) {   // 48 rows x 160 chunks
    int r = ci2 / 160, q = ci2 - r * 160;
    bf16x8 v = *(const bf16x8*)&kw[r * 1288 + q * 8];
    *(bf16x8*)&Q[qb + (long)r * 1280 + q * 8] = v;
    float s = 0.f;
    #pragma unroll
    for (int j = 0; j < 8; ++j) { float f = b2f(v[j]); s += f * f; }
    atomicAdd(&ssrow[r], s);
  }
  __syncthreads();
  if (tid < 48)
    inv[(long)b * 3072 + c * 48 + tid] = 1.0f / fmaxf(sqrtf(ssrow[tid]), 1e-12f);
  // QT: for each k, write 48-short column chunk (96B) at m = c*48
  long qtb = (long)b * 3932160L + (long)c * 48;
  for (int k = tid; k < 1280; k += 256) {
    short tmp[48];
    #pragma unroll
    for (int r = 0; r < 48; ++r) tmp[r] = kw[r * 1288 + k];
    short* dst = &QT[qtb + (long)k * 3072];
    #pragma unroll
    for (int q = 0; q < 6; ++q)
      *(bf16x8*)&dst[q * 8] = *(const bf16x8*)&tmp[q * 8];
  }
}

// ---------------- merged af+sa permute+transpose + fused sumsq atomics ----------------
__global__ __launch_bounds__(256) void permtr_all_k(const float* __restrict__ x,
    short* __restrict__ Qaf, short* __restrict__ QTaf,
    short* __restrict__ Qsa, short* __restrict__ QTsa,
    float* __restrict__ ssaf, float* __restrict__ sssa) {
  __shared__ short t[32][33];
  int bid = blockIdx.x;
  int isAF = (bid < 17280);
  int M, Mp, Kp, kt, mt, b;
  short *Q, *QT; float* ss;
  if (isAF) { M = 320; Mp = 384; Kp = 11520; kt = bid % 360; int r = bid / 360; mt = r % 12; b = r / 12;
              Q = Qaf; QT = QTaf; ss = ssaf; }
  else { int id = bid - 17280; M = 240; Mp = 256; Kp = 15360; kt = id % 480; int r = id / 480; mt = r % 8; b = r / 8;
         Q = Qsa; QT = QTsa; ss = sssa; }
  int k0 = kt * 32, m0 = mt * 32;
  int tx = threadIdx.x & 31, ty = threadIdx.x >> 5;
  const float* xb = x + (long)b * 3686400;
  #pragma unroll
  for (int i = 0; i < 32; i += 8) {
    int m = m0 + ty + i, k = k0 + tx;
    float v = 0.f;
    if (m < M) {
      int q1 = k / 240, r2 = k - q1 * 240;
      int v5 = r2 / 48, wv = r2 - v5 * 48;
      int a1 = m / 5, u = m - a1 * 5;
      long xi = isAF ? ((long)a1 * 25 + u * 5 + v5) * 2304 + q1 * 48 + wv
                     : ((long)q1 * 25 + u * 5 + v5) * 2304 + a1 * 48 + wv;
      v = xb[xi];
    }
    t[ty + i][tx] = f2b(v);
  }
  __syncthreads();
  long Qb = (long)b * Mp * Kp;
  #pragma unroll
  for (int i = 0; i < 32; i += 8)
    Q[Qb + (long)(m0 + ty + i) * Kp + k0 + tx] = t[ty + i][tx];
  #pragma unroll
  for (int i = 0; i < 32; i += 8)
    QT[Qb + (long)(k0 + ty + i) * Mp + m0 + tx] = t[tx][ty + i];
  if (threadIdx.x < 32 && m0 + (int)threadIdx.x < M) {
    float s = 0.f;
    #pragma unroll
    for (int k = 0; k < 32; ++k) { float f = b2f(t[threadIdx.x][k]); s += f * f; }
    atomicAdd(&ss[b * Mp + m0 + threadIdx.x], s);
  }
}

// ---------------- sf GEMM1: triangular, BK=64 2-phase dbuf; P=exp(cos)+rowsums --------
__global__ __launch_bounds__(256, 2) void gemm1_tri_k(const short* __restrict__ Q,
                                                      const float* __restrict__ invn,
                                                      short* __restrict__ att,
                                                      float* __restrict__ rowsum) {
  __shared__ short sm[32768];
  int tid = threadIdx.x, wave = tid >> 6, lane = tid & 63;
  int la = lane & 15, lb = lane >> 4;
  int bat = blockIdx.z;
  int bx = blockIdx.x, yt = 0, rem = bx;
  while (rem >= 24 - yt) { rem -= 24 - yt; ++yt; }
  int xt = yt + rem;
  const short* Qb = Q + (long)bat * 3932160L;
  const float* inv = invn + (long)bat * 3072;
  int row0 = yt * 128, col0 = xt * 128;
  f32x4 acc[4][4] = {};
  int wr = wave >> 1, wc = wave & 1;
  int rloc = tid >> 3, cbase = (tid & 7) * 8;
  int ldsoff = tid * 8;

  const short *pA[4], *pB[4];
  #pragma unroll
  for (int p = 0; p < 4; ++p) {
    int row = p * 32 + rloc;
    int sc = SWZ(row, cbase);
    pA[p] = Qb + (long)(row0 + row) * 1280 + sc;
    pB[p] = Qb + (long)(col0 + row) * 1280 + sc;
  }

  #define TRI_STAGE(KT, BUF) { \
    short* Asb = sm + (BUF) * 16384; \
    short* Bsb = Asb + 8192; \
    _Pragma("unroll") \
    for (int p = 0; p < 4; ++p) { \
      gload16(pA[p] + (KT) * 64, (void*)(Asb + p * 2048 + ldsoff)); \
      gload16(pB[p] + (KT) * 64, (void*)(Bsb + p * 2048 + ldsoff)); \
    } }
  #define TRI_COMP(BUF) { \
    const short* Asb = sm + (BUF) * 16384; \
    const short* Bsb = Asb + 8192; \
    _Pragma("unroll") \
    for (int kk = 0; kk < 64; kk += 32) { \
      bf16x8 av[4], bv[4]; \
      _Pragma("unroll") \
      for (int m = 0; m < 4; ++m) \
        av[m] = *(const bf16x8*)&Asb[(wr * 64 + m * 16 + la) * 64 + SWZ(la, kk + lb * 8)]; \
      _Pragma("unroll") \
      for (int nn = 0; nn < 4; ++nn) \
        bv[nn] = *(const bf16x8*)&Bsb[(wc * 64 + nn * 16 + la) * 64 + SWZ(la, kk + lb * 8)]; \
      _Pragma("unroll") \
      for (int m = 0; m < 4; ++m) \
        _Pragma("unroll") \
        for (int nn = 0; nn < 4; ++nn) \
          acc[m][nn] = __builtin_amdgcn_mfma_f32_16x16x32_bf16(av[m], bv[nn], acc[m][nn], 0, 0, 0); \
    } }

  TRI_STAGE(0, 0)
  for (int kt = 0; kt < 19; ++kt) {
    TRI_STAGE(kt + 1, (kt + 1) & 1)
    asm volatile("s_waitcnt vmcnt(8)" ::: "memory");
    __builtin_amdgcn_s_barrier();
    TRI_COMP(kt & 1)
    asm volatile("" ::: "memory");
    __builtin_amdgcn_s_barrier();
  }
  asm volatile("s_waitcnt vmcnt(0)" ::: "memory");
  __builtin_amdgcn_s_barrier();
  TRI_COMP(1)
  asm volatile("" ::: "memory");
  __builtin_amdgcn_s_barrier();

  short* staged = sm;
  #pragma unroll
  for (int m = 0; m < 4; ++m) {
    #pragma unroll
    for (int nn = 0; nn < 4; ++nn) {
      int cl = wc * 64 + nn * 16 + la;
      float ic = inv[col0 + cl];
      #pragma unroll
      for (int j = 0; j < 4; ++j) {
        int rl = wr * 64 + m * 16 + lb * 4 + j;
        staged[rl * 136 + cl] = f2b(__expf(acc[m][nn][j] * inv[row0 + rl] * ic));
      }
    }
  }
  __syncthreads();
  short* attb = att + (long)bat * 9437184L;
  float* rsb = rowsum + (long)bat * 3072;
  {
    int r = tid >> 1, half = tid & 1;
    short* dst = attb + (long)(row0 + r) * 3072 + col0 + half * 64;
    const short* src = &staged[r * 136 + half * 64];
    float s = 0.f;
    #pragma unroll
    for (int q = 0; q < 8; ++q) {
      bf16x8 v = *(const bf16x8*)&src[q * 8];
      *(bf16x8*)&dst[q * 8] = v;
      #pragma unroll
      for (int jj = 0; jj < 8; ++jj) s += b2f(v[jj]);
    }
    s += __shfl_xor(s, 1, 64);
    if (half == 0) atomicAdd(&rsb[row0 + r], s);
  }
  if (xt != yt) {
    int c = tid >> 1, half = tid & 1;
    short* dst = attb + (long)(col0 + c) * 3072 + row0 + half * 64;
    float s = 0.f;
    #pragma unroll
    for (int q = 0; q < 8; ++q) {
      bf16x8 o;
      #pragma unroll
      for (int jj = 0; jj < 8; ++jj) {
        o[jj] = staged[(half * 64 + q * 8 + jj) * 136 + c];
        s += b2f(o[jj]);
      }
      *(bf16x8*)&dst[q * 8] = o;
    }
    s += __shfl_xor(s, 1, 64);
    if (half == 0) atomicAdd(&rsb[col0 + c], s);
  }
}

// ---------------- merged af+sa GEMM1: raw f32 S, split-K atomics, BK=64 dbuf ----------
__global__ __launch_bounds__(256, 2) void gemm_s_all_k(
    const short* __restrict__ Aaf, const short* __restrict__ Asa,
    float* __restrict__ Sfaf, float* __restrict__ Sfsa)
{
  __shared__ short sm[32768];
  int bid = blockIdx.x;
  const short* A; float* Sf;
  int lda, ktotal, ksper, ldc, row0, col0, bat, kc;
  long sA, sS;
  if (bid < 288) {
    int txy = bid % 9, z = bid / 9;
    col0 = (txy % 3) * 128; row0 = (txy / 3) * 128;
    bat = z / 8; kc = z % 8;
    lda = 11520; ktotal = 180; ksper = 23; ldc = 384;
    sA = 4423680L; sS = 147456L; A = Aaf; Sf = Sfaf;
  } else {
    int id = bid - 288;
    int txy = id % 4, z = id / 4;
    col0 = (txy % 2) * 128; row0 = (txy / 2) * 128;
    bat = z / 16; kc = z % 16;
    lda = 15360; ktotal = 240; ksper = 15; ldc = 256;
    sA = 3932160L; sS = 65536L; A = Asa; Sf = Sfsa;
  }
  int tid = threadIdx.x;
  int wave = tid >> 6, lane = tid & 63;
  int la = lane & 15, lb = lane >> 4;
  const short* Ab = A + (long)bat * sA;
  int kb = kc * ksper, ke = min(ktotal, kb + ksper);
  int L = ke - kb;
  f32x4 acc[4][4] = {};
  int wr = wave >> 1, wc = wave & 1;
  int rloc = tid >> 3, cbase = (tid & 7) * 8;
  int ldsoff = tid * 8;

  const short *pA[4], *pB[4];
  #pragma unroll
  for (int p = 0; p < 4; ++p) {
    int row = p * 32 + rloc;
    int sc = SWZ(row, cbase);
    pA[p] = Ab + (long)(row0 + row) * lda + sc;
    pB[p] = Ab + (long)(col0 + row) * lda + sc;
  }

  #define GS_STAGE(KT, BUF) { \
    short* Asb = sm + (BUF) * 16384; \
    short* Bsb = Asb + 8192; \
    _Pragma("unroll") \
    for (int p = 0; p < 4; ++p) { \
      gload16(pA[p] + (KT) * 64, (void*)(Asb + p * 2048 + ldsoff)); \
      gload16(pB[p] + (KT) * 64, (void*)(Bsb + p * 2048 + ldsoff)); \
    } }
  #define GS_COMP(BUF) { \
    const short* Asb = sm + (BUF) * 16384; \
    const short* Bsb = Asb + 8192; \
    _Pragma("unroll") \
    for (int kk = 0; kk < 64; kk += 32) { \
      bf16x8 av[4], bv[4]; \
      _Pragma("unroll") \
      for (int m = 0; m < 4; ++m) \
        av[m] = *(const bf16x8*)&Asb[(wr * 64 + m * 16 + la) * 64 + SWZ(la, kk + lb * 8)]; \
      _Pragma("unroll") \
      for (int nn = 0; nn < 4; ++nn) \
        bv[nn] = *(const bf16x8*)&Bsb[(wc * 64 + nn * 16 + la) * 64 + SWZ(la, kk + lb * 8)]; \
      _Pragma("unroll") \
      for (int m = 0; m < 4; ++m) \
        _Pragma("unroll") \
        for (int nn = 0; nn < 4; ++nn) \
          acc[m][nn] = __builtin_amdgcn_mfma_f32_16x16x32_bf16(av[m], bv[nn], acc[m][nn], 0, 0, 0); \
    } }

  GS_STAGE(kb, 0)
  for (int t = 0; t < L - 1; ++t) {
    GS_STAGE(kb + t + 1, (t + 1) & 1)
    asm volatile("s_waitcnt vmcnt(8)" ::: "memory");
    __builtin_amdgcn_s_barrier();
    GS_COMP(t & 1)
    asm volatile("" ::: "memory");
    __builtin_amdgcn_s_barrier();
  }
  asm volatile("s_waitcnt vmcnt(0)" ::: "memory");
  __builtin_amdgcn_s_barrier();
  GS_COMP((L - 1) & 1)

  float* Sb = Sf + (long)bat * sS;
  #pragma unroll
  for (int m = 0; m < 4; ++m) {
    int gr0 = row0 + wr * 64 + m * 16 + lb * 4;
    #pragma unroll
    for (int nn = 0; nn < 4; ++nn) {
      int gc = col0 + wc * 64 + nn * 16 + la;
      #pragma unroll
      for (int j = 0; j < 4; ++j)
        atomicAdd(&Sb[(long)(gr0 + j) * ldc + gc], acc[m][nn][j]);
    }
  }
}

// ---------------- merged af+sa softmax: row-per-wave, in-register ----------------
__global__ __launch_bounds__(256) void softmax_all_k(
    const float* __restrict__ Sfaf, const float* __restrict__ Sfsa,
    const float* __restrict__ ssaf, const float* __restrict__ sssa,
    short* __restrict__ attaf, short* __restrict__ attsa)
{
  int wave = threadIdx.x >> 6, lane = threadIdx.x & 63;
  int rid = blockIdx.x * 4 + wave;
  int row, b, Mv, Mp; const float *Sf, *ss; short* att;
  if (rid < 1280) { row = rid % 320; b = rid / 320; Mv = 320; Mp = 384; Sf = Sfaf; ss = ssaf; att = attaf; }
  else { int id = rid - 1280; row = id % 240; b = id / 240; Mv = 240; Mp = 256; Sf = Sfsa; ss = sssa; att = attsa; }
  long sS = (long)Mp * Mp;
  const float* Sr = Sf + (long)b * sS + (long)row * Mp;
  const float* ssb = ss + b * Mp;
  float inv_i = rsqrtf(fmaxf(ssb[row], 1e-24f));
  float ev[6] = {0.f, 0.f, 0.f, 0.f, 0.f, 0.f};
  float sum = 0.f;
  #pragma unroll
  for (int q = 0; q < 6; ++q) {
    int j = q * 64 + lane;
    if (j < Mv) {
      float e = __expf(Sr[j] * inv_i * rsqrtf(fmaxf(ssb[j], 1e-24f)));
      ev[q] = e; sum += e;
    }
  }
  #pragma unroll
  for (int o = 32; o >= 1; o >>= 1) sum += __shfl_xor(sum, o, 64);
  float rden = 1.0f / sum;
  short* ar = att + (long)b * sS + (long)row * Mp;
  #pragma unroll
  for (int q = 0; q < 6; ++q) {
    int j = q * 64 + lane;
    if (j < Mp) ar[j] = (j < Mv) ? f2b(ev[q] * rden) : (short)0;
  }
}

// ---------------- sf GEMM2: 256x256 tile, 8 waves, 4-phase counted-vmcnt dbuf ----------
__global__ __launch_bounds__(512) void gemm2sf_k(const short* __restrict__ A,
                                                 const short* __restrict__ B,
                                                 const float* __restrict__ rowsum,
                                                 short* __restrict__ F) {
  __shared__ short sm[65536];     // 131072 B
  int tid = threadIdx.x;
  int wave = tid >> 6, lane = tid & 63;
  int la = lane & 15, lb = lane >> 4;
  int wr = wave >> 2, wc = wave & 3;
  int wk;
  { int xcd = blockIdx.x & 7, j = blockIdx.x >> 3; wk = xcd * 30 + j; }
  int yt = wk % 12, rem = wk / 12;
  int xt = rem % 5, bat = rem / 5;
  const short* Ab = A + (long)bat * 9437184L;
  const short* Bb = B + (long)bat * 3932160L;
  int rloc = tid >> 3;
  int cbase = (tid & 7) * 8;
  int sc = cbase ^ ((rloc & 7) << 3);
  const short *pAg[4], *pBg[4];
  #pragma unroll
  for (int g = 0; g < 4; ++g) {
    pAg[g] = Ab + (long)(rloc * 48 + yt * 4 + g) * 3072 + sc;
    pBg[g] = Bb + (long)(xt * 256 + g * 64 + rloc) * 3072 + sc;
  }
  f32x4 acc[8][4] = {};

  #pragma unroll
  for (int g = 0; g < 4; ++g) {
    gload16(pAg[g], (void*)(sm + g * 4096 + tid * 8));
    gload16(pBg[g], (void*)(sm + 16384 + g * 4096 + tid * 8));
  }
  asm volatile("s_waitcnt vmcnt(0)" ::: "memory");
  __builtin_amdgcn_s_barrier();

  #define G2_PHASE(MH, KK, LOADB) { \
    if (LOADB) { \
      _Pragma("unroll") \
      for (int nn = 0; nn < 4; ++nn) \
        bv[nn] = *(const bf16x8*)&Bsb[(wc * 64 + nn * 16 + la) * 64 + SWZ(la, (KK) + lb * 8)]; \
    } \
    _Pragma("unroll") \
    for (int m = 0; m < 4; ++m) \
      av[m] = *(const bf16x8*)&Asb[(wr * 128 + (MH) * 64 + m * 16 + la) * 64 + SWZ(la, (KK) + lb * 8)]; \
    __builtin_amdgcn_s_setprio(1); \
    _Pragma("unroll") \
    for (int m = 0; m < 4; ++m) \
      _Pragma("unroll") \
      for (int nn = 0; nn < 4; ++nn) \
        acc[(MH) * 4 + m][nn] = __builtin_amdgcn_mfma_f32_16x16x32_bf16(av[m], bv[nn], acc[(MH) * 4 + m][nn], 0, 0, 0); \
    __builtin_amdgcn_s_setprio(0); \
  }

  for (int t = 0; t < 48; ++t) {
    const short* Asb = sm + (t & 1) * 32768;
    const short* Bsb = Asb + 16384;
    short* An = sm + ((t + 1) & 1) * 32768;
    short* Bn = An + 16384;
    int k1 = (t + 1) * 64;
    bool pf = (t < 47);
    bf16x8 av[4], bv[4];

    // phase 0
    asm volatile("s_waitcnt vmcnt(2)" ::: "memory");
    __builtin_amdgcn_s_barrier();
    if (pf) { gload16(pBg[0] + k1, (void*)(Bn + tid * 8));
              gload16(pBg[1] + k1, (void*)(Bn + 4096 + tid * 8)); }
    G2_PHASE(0, 0, 1)
    // phase 1 (final iteration must fully drain: A-odd of last prefetch unconfirmed otherwise)
    if (pf) asm volatile("s_waitcnt vmcnt(2)" ::: "memory");
    else    asm volatile("s_waitcnt vmcnt(0)" ::: "memory");
    __builtin_amdgcn_s_barrier();
    if (pf) { gload16(pBg[2] + k1, (void*)(Bn + 8192 + tid * 8));
              gload16(pBg[3] + k1, (void*)(Bn + 12288 + tid * 8)); }
    G2_PHASE(1, 0, 0)
    // phase 2
    asm volatile("s_waitcnt vmcnt(4)" ::: "memory");
    __builtin_amdgcn_s_barrier();
    if (pf) { gload16(pAg[0] + k1, (void*)(An + tid * 8));
              gload16(pAg[2] + k1, (void*)(An + 8192 + tid * 8)); }
    G2_PHASE(0, 32, 1)
    // phase 3
    asm volatile("s_waitcnt vmcnt(6)" ::: "memory");
    __builtin_amdgcn_s_barrier();
    if (pf) { gload16(pAg[1] + k1, (void*)(An + 4096 + tid * 8));
              gload16(pAg[3] + k1, (void*)(An + 12288 + tid * 8)); }
    G2_PHASE(1, 32, 0)
  }
  __syncthreads();

  const float* rsb = rowsum + (long)bat * 3072;
  float rs[8][4];
  #pragma unroll
  for (int m = 0; m < 8; ++m) {
    int sub = wr * 2 + (m >> 2);
    #pragma unroll
    for (int j = 0; j < 4; ++j) {
      int cc = (m & 3) * 16 + lb * 4 + j;
      rs[m][j] = 1.0f / rsb[cc * 48 + yt * 4 + sub];
    }
  }
  short* staged = sm;
  #pragma unroll
  for (int m = 0; m < 8; ++m) {
    int sub = wr * 2 + (m >> 2);
    #pragma unroll
    for (int nn = 0; nn < 4; ++nn) {
      int gcl = wc * 64 + nn * 16 + la;
      int chunk = gcl * 4 + sub;
      int key = (gcl & 7) << 3;
      short4 o;
      o.x = f2b(acc[m][nn][0] * rs[m][0]); o.y = f2b(acc[m][nn][1] * rs[m][1]);
      o.z = f2b(acc[m][nn][2] * rs[m][2]); o.w = f2b(acc[m][nn][3] * rs[m][3]);
      *(short4*)&staged[chunk * 64 + (((m & 3) * 16 + lb * 4) ^ key)] = o;
    }
  }
  __syncthreads();
  #pragma unroll
  for (int i = 0; i < 16; ++i) {
    int chunk = i * 64 + (tid >> 3);
    int part = tid & 7;
    int gcl = chunk >> 2, sub = chunk & 3;
    int key = (gcl & 7) << 3;
    bf16x8 v = *(const bf16x8*)&staged[chunk * 64 + ((part * 8) ^ key)];
    int gc = xt * 256 + gcl;
    if (gc < 1200) {
      int hh = yt * 4 + sub;
      int wv = gc / 25, nidx = gc - wv * 25;
      long base = (((long)(bat * 48 + hh) * 48 + wv) * 25 + nidx) * 192 + part * 8;
      *(bf16x8*)&F[base] = v;
    }
  }
}

// ---------------- merged af+sa GEMM2 (1-phase) with XCD swizzle ----------------
__global__ __launch_bounds__(256) void gemm2_afsa_k(
    const short* __restrict__ attaf, const short* __restrict__ QTaf,
    const short* __restrict__ attsa, const short* __restrict__ QTsa,
    short* __restrict__ F)
{
  __shared__ short sm[20480];
  short* As = sm;
  short* Bs = sm + 4096;
  int bid = blockIdx.x;
  int isAF = (bid < 900);
  int NX, NY, LDA, KST, wk;
  const short *A, *B; long SA, SB;
  if (isAF) {
    NX = 45; NY = 5; LDA = 384; KST = 6; SA = 147456L; SB = 4423680L; A = attaf; B = QTaf;
    int xcd = bid & 7, j = bid >> 3;
    wk = (xcd < 4) ? xcd * 113 + j : 4 * 113 + (xcd - 4) * 112 + j;
  } else {
    NX = 60; NY = 4; LDA = 256; KST = 4; SA = 65536L; SB = 3932160L; A = attsa; B = QTsa;
    int id = bid - 900;
    int xcd = id & 7, j = id >> 3;
    wk = xcd * 120 + j;
  }
  int yt = wk % NY, rem = wk / NY;
  int xt = rem % NX, bat = rem / NX;
  int tid = threadIdx.x, wave = tid >> 6, lane = tid & 63;
  int la = lane & 15, lb = lane >> 4;
  const short* Ab = A + (long)bat * SA;
  const short* Bb = B + (long)bat * SB;
  f32x4 acc[4][4] = {};
  int rloc = tid >> 3, cbase = (tid & 7) * 8;
  int ldsoff = tid * 8;

  const short *pA[2], *pB[8];
  #pragma unroll
  for (int p = 0; p < 2; ++p) {
    int r = p * 32 + rloc;
    int sc = SWZ(r, cbase);
    int rowg = isAF ? (r * 5 + yt) : (yt * 64 + r);
    pA[p] = Ab + (long)rowg * LDA + sc;
  }
  #pragma unroll
  for (int p = 0; p < 8; ++p) {
    int rb = p * 32 + rloc;
    int sc = SWZ(rb, cbase);
    int rowg;
    if (isAF) rowg = xt * 256 + rb;
    else { int c = rb & 63, g = rb >> 6; rowg = c * 240 + xt * 4 + g; }
    pB[p] = Bb + (long)rowg * LDA + sc;
  }

  for (int kt = 0; kt < KST; ++kt) {
    #pragma unroll
    for (int p = 0; p < 2; ++p)
      gload16(pA[p] + kt * 64, (void*)(As + p * 2048 + ldsoff));
    #pragma unroll
    for (int p = 0; p < 8; ++p)
      gload16(pB[p] + kt * 64, (void*)(Bs + p * 2048 + ldsoff));
    __syncthreads();
    #pragma unroll
    for (int kk = 0; kk < 64; kk += 32) {
      bf16x8 av[4], bv[4];
      #pragma unroll
      for (int m = 0; m < 4; ++m)
        av[m] = *(const bf16x8*)&As[(m * 16 + la) * 64 + SWZ(la, kk + lb * 8)];
      #pragma unroll
      for (int nn = 0; nn < 4; ++nn)
        bv[nn] = *(const bf16x8*)&Bs[(wave * 64 + nn * 16 + la) * 64 + SWZ(la, kk + lb * 8)];
      #pragma unroll
      for (int m = 0; m < 4; ++m)
        #pragma unroll
        for (int nn = 0; nn < 4; ++nn)
          acc[m][nn] = __builtin_amdgcn_mfma_f32_16x16x32_bf16(av[m], bv[nn], acc[m][nn], 0, 0, 0);
    }
    __syncthreads();
  }

  short* staged = sm;
  #pragma unroll
  for (int m = 0; m < 4; ++m) {
    #pragma unroll
    for (int nn = 0; nn < 4; ++nn) {
      if (!isAF) {
        #pragma unroll
        for (int j = 0; j < 4; ++j)
          staged[((m * 16 + lb * 4 + j) * 4 + wave) * 72 + nn * 16 + la] = f2b(acc[m][nn][j]);
      } else {
        short4 o;
        o.x = f2b(acc[m][nn][0]); o.y = f2b(acc[m][nn][1]);
        o.z = f2b(acc[m][nn][2]); o.w = f2b(acc[m][nn][3]);
        *(short4*)&staged[(wave * 64 + nn * 16 + la) * 72 + m * 16 + lb * 4] = o;
      }
    }
  }
  __syncthreads();

  #pragma unroll
  for (int rd = 0; rd < 8; ++rd) {
    int chunk = rd * 32 + (tid >> 3);
    int part = tid & 7;
    bf16x8 v = *(const bf16x8*)&staged[chunk * 72 + part * 8];
    long base; bool ok = true;
    if (isAF) {
      int gc = xt * 256 + chunk;
      int hh = gc / 240, r2 = gc - hh * 240, v5 = r2 / 48, wv = r2 - v5 * 48;
      base = (((long)(bat * 48 + hh) * 48 + wv) * 25 + yt * 5 + v5) * 192 + 64 + part * 8;
    } else {
      int r = chunk >> 2, g = chunk & 3;
      int gr = yt * 64 + r; ok = (gr < 240);
      int hh = gr / 5, u = gr - hh * 5;
      int r2 = xt * 4 + g, v5 = r2 / 48, wv = r2 - v5 * 48;
      base = (((long)(bat * 48 + hh) * 48 + wv) * 25 + u * 5 + v5) * 192 + 128 + part * 8;
    }
    if (ok) *(bf16x8*)&F[base] = v;
  }
}

// ---------------- weight prep ----------------
__global__ __launch_bounds__(256) void prep_w_k(const float* __restrict__ w1, const float* __restrict__ w2,
                                                short* __restrict__ w1t, short* __restrict__ w2t) {
  int idx = blockIdx.x * 256 + threadIdx.x;
  if (idx < 12288) {
    int i = idx / 64, j = idx - i * 64;
    w1t[j * 192 + i] = f2b(w1[idx]);
  } else if (idx < 16384) {
    int k = idx - 12288;
    int i = k / 64, j = k - i * 64;
    w2t[j * 64 + i] = f2b(w2[k]);
  }
}

// ---------------- fused (+x) LayerNorm + MFMA MLP + residual ----------------
__global__ __launch_bounds__(256) void ln_mlp_mfma_k(
    const short* __restrict__ F, const float* __restrict__ x,
    const float* __restrict__ gamma, const float* __restrict__ beta,
    const short* __restrict__ w1t, const short* __restrict__ w2t,
    float* __restrict__ out)
{
  int n = blockIdx.x, hh = blockIdx.y, b = blockIdx.z;
  __shared__ short A1[48 * 200];
  __shared__ float xs[64 * 49];
  __shared__ __align__(16) char pool[19584];
  short* Fs = (short*)pool;
  short* Y1 = (short*)pool;
  float* Y2 = (float*)(pool + 6912);
  int tid = threadIdx.x, wave = tid >> 6, lane = tid & 63;
  int la = lane & 15, lb = lane >> 4;
  long Fb0 = ((long)(b * 48 + hh) * 1200 + n) * 192;
  long xb = (long)b * 3686400 + (long)n * 2304 + hh * 48;

  #pragma unroll
  for (int it = 0; it < 5; ++it) {
    int ci = tid + 256 * it;
    if (ci < 1152) {
      int r = ci / 24, q = ci - r * 24;
      gload16(&F[Fb0 + (long)r * 4800 + q * 8], (void*)(Fs + ci * 8));
    }
  }
  {
    int ch = tid >> 2, qq = tid & 3;
    const float* xr = x + xb + (long)ch * 57600 + qq * 12;
    #pragma unroll
    for (int i = 0; i < 12; ++i) xs[ch * 49 + qq * 12 + i] = xr[i];
  }
  __syncthreads();

  float g0 = gamma[lane], g1 = gamma[lane + 64], g2 = gamma[lane + 128];
  float bt0 = beta[lane], bt1 = beta[lane + 64], bt2 = beta[lane + 128];
  #pragma unroll 4
  for (int rr = 0; rr < 12; ++rr) {
    int r = wave * 12 + rr;
    float xv = xs[lane * 49 + r];
    float v0 = b2f(Fs[r * 192 + lane]) + xv;
    float v1 = b2f(Fs[r * 192 + lane + 64]) + xv;
    float v2 = b2f(Fs[r * 192 + lane + 128]) + xv;
    float s = v0 + v1 + v2;
    #pragma unroll
    for (int o = 32; o >= 1; o >>= 1) s += __shfl_xor(s, o, 64);
    float mu = s * (1.f / 192.f);
    float d0 = v0 - mu, d1 = v1 - mu, d2 = v2 - mu;
    float q = d0 * d0 + d1 * d1 + d2 * d2;
    #pragma unroll
    for (int o = 32; o >= 1; o >>= 1) q += __shfl_xor(q, o, 64);
    float rsq = rsqrtf(q * (1.f / 192.f) + 1e-5f);
    A1[r * 200 + lane]       = f2b(d0 * rsq * g0 + bt0);
    A1[r * 200 + lane + 64]  = f2b(d1 * rsq * g1 + bt1);
    A1[r * 200 + lane + 128] = f2b(d2 * rsq * g2 + bt2);
  }
  __syncthreads();

  f32x4 acc1[3] = {};
  #pragma unroll
  for (int ks = 0; ks < 6; ++ks) {
    bf16x8 bv = *(const bf16x8*)&w1t[(wave * 16 + la) * 192 + ks * 32 + lb * 8];
    #pragma unroll
    for (int m = 0; m < 3; ++m) {
      bf16x8 av = *(const bf16x8*)&A1[(m * 16 + la) * 200 + ks * 32 + lb * 8];
      acc1[m] = __builtin_amdgcn_mfma_f32_16x16x32_bf16(av, bv, acc1[m], 0, 0, 0);
    }
  }
  #pragma unroll
  for (int m = 0; m < 3; ++m)
    #pragma unroll
    for (int j = 0; j < 4; ++j)
      Y1[(m * 16 + lb * 4 + j) * 72 + wave * 16 + la] = f2b(fmaxf(acc1[m][j], 0.f));
  __syncthreads();

  f32x4 acc2[3] = {};
  #pragma unroll
  for (int ks = 0; ks < 2; ++ks) {
    bf16x8 bv = *(const bf16x8*)&w2t[(wave * 16 + la) * 64 + ks * 32 + lb * 8];
    #pragma unroll
    for (int m = 0; m < 3; ++m) {
      bf16x8 av = *(const bf16x8*)&Y1[(m * 16 + la) * 72 + ks * 32 + lb * 8];
      acc2[m] = __builtin_amdgcn_mfma_f32_16x16x32_bf16(av, bv, acc2[m], 0, 0, 0);
    }
  }
  #pragma unroll
  for (int m = 0; m < 3; ++m)
    #pragma unroll
    for (int j = 0; j < 4; ++j)
      Y2[(m * 16 + lb * 4 + j) * 66 + wave * 16 + la] = acc2[m][j];
  __syncthreads();

  #pragma unroll
  for (int i = 0; i < 12; ++i) {
    int e = tid + 256 * i;
    int cc = e / 48, wv = e - cc * 48;
    out[xb + (long)cc * 57600 + wv] = Y2[wv * 66 + cc] + xs[cc * 49 + wv];
  }
}

// ---------------- host launcher ----------------
extern "C" void kernel_launch(void* const* d_in, const int* in_sizes, int n_in,
                              void* d_out, int out_size, void* d_ws, size_t ws_size,
                              hipStream_t stream) {
  (void)in_sizes; (void)n_in; (void)out_size;
  const float* x     = (const float*)d_in[0];
  const float* gamma = (const float*)d_in[1];
  const float* beta  = (const float*)d_in[2];
  const float* w1    = (const float*)d_in[3];
  const float* w2    = (const float*)d_in[4];
  float* out = (float*)d_out;

  const size_t NEED = 237191168UL;
  if (ws_size < NEED) return;
  char* ws = (char*)d_ws;
  short* F     = (short*)(ws);
  short* attsf = (short*)(ws + 88473600UL);
  short* Qsf   = (short*)(ws + 163971072UL);
  short* QTsf  = (short*)(ws + 199360512UL);
  float* rowsum = (float*)(ws + 234749952UL);
  float* invn  = (float*)(ws + 237109248UL);
  short* w1t   = (short*)(ws + 237158400UL);
  short* w2t   = (short*)(ws + 237182976UL);
  // phase 2 (af+sa) reuses sf regions
  short* Qaf   = (short*)(ws + 88473600UL);
  short* QTaf  = (short*)(ws + 123863040UL);
  float* Sfsa  = (float*)(ws + 159252480UL);
  float* ssaf  = (float*)(ws + 160301056UL);
  float* sssa  = (float*)(ws + 160307200UL);
  short* attaf = (short*)(ws + 160311296UL);
  short* attsa = (short*)(ws + 161490944UL);
  short* Qsa   = (short*)(ws + 163971072UL);
  short* QTsa  = (short*)(ws + 195428352UL);
  float* Sfaf  = (float*)(ws + 234749952UL);

  prep_w_k<<<64, 256, 0, stream>>>(w1, w2, w1t, w2t);

  // ================= SF =================
  permute_sf2_k<<<dim3(64, 4), 256, 0, stream>>>(x, Qsf, QTsf, invn, rowsum);
  gemm1_tri_k<<<dim3(300, 1, 4), 256, 0, stream>>>(Qsf, invn, attsf, rowsum);
  gemm2sf_k<<<dim3(240), 512, 0, stream>>>(attsf, QTsf, rowsum, F);

  // ================= AF + SA merged =================
  hipMemsetAsync(Sfaf, 0, 2359296, stream);
  hipMemsetAsync((char*)Sfsa, 0, 1058816, stream);   // Sfsa + ssaf + sssa (contiguous)
  permtr_all_k<<<32640, 256, 0, stream>>>(x, Qaf, QTaf, Qsa, QTsa, ssaf, sssa);
  gemm_s_all_k<<<544, 256, 0, stream>>>(Qaf, Qsa, Sfaf, Sfsa);
  softmax_all_k<<<560, 256, 0, stream>>>(Sfaf, Sfsa, ssaf, sssa, attaf, attsa);
  gemm2_afsa_k<<<1860, 256, 0, stream>>>(attaf, QTaf, attsa, QTsa, F);

  // ================= LN + MLP + residual =================
  ln_mlp_mfma_k<<<dim3(25, 48, 4), 256, 0, stream>>>(F, x, gamma, beta, w1t, w2t, out);
}

// Round 13
// 466.511 us; speedup vs baseline: 1.0259x; 1.0259x over previous
//
#include <hip/hip_runtime.h>
#include <stdint.h>

typedef __attribute__((ext_vector_type(8))) short bf16x8;
typedef __attribute__((ext_vector_type(4))) float f32x4;

__device__ __forceinline__ float b2f(short s) {
  union { unsigned u; float f; } a; a.u = ((unsigned)(unsigned short)s) << 16; return a.f;
}
__device__ __forceinline__ short f2b(float f) {
  union { float f; unsigned u; } a; a.f = f;
  unsigned r = a.u + 0x7fffu + ((a.u >> 16) & 1u);
  return (short)(r >> 16);
}
__device__ __forceinline__ void gload16(const void* g, void* l) {
  __builtin_amdgcn_global_load_lds((__attribute__((address_space(1))) void*)g,
                                   (__attribute__((address_space(3))) void*)l, 16, 0, 0);
}

// LDS XOR swizzle (T2, rule-21 form)
#define SWZ(row, col) ((col) ^ (((row) & 7) << 3))

// ---------------- SF permute + fused row inv-norm (proven R11) ----------------
__global__ __launch_bounds__(256) void permute_sf_k(const float* __restrict__ x,
                                                    short* __restrict__ Q,
                                                    float* __restrict__ inv) {
  __shared__ float buf[4][1200];
  int wave = threadIdx.x >> 6, lane = threadIdx.x & 63;
  int gr = blockIdx.x * 4 + wave;
  int b = gr / 3072, m = gr - b * 3072;
  int c = m / 48, hh = m - c * 48;
  const float* xb = x + (long)(b * 64 + c) * 57600 + hh * 48;
  for (int uv = 0; uv < 25; ++uv)
    if (lane < 48) buf[wave][uv * 48 + lane] = xb[uv * 2304 + lane];
  __syncthreads();
  short* Qr = Q + (long)gr * 1280;
  float ss = 0.f;
  for (int k = lane; k < 1280; k += 64) {
    float v = 0.f;
    if (k < 1200) { int wv = k / 25, uv = k - wv * 25; v = buf[wave][uv * 48 + wv]; }
    ss += v * v;
    Qr[k] = f2b(v);
  }
  #pragma unroll
  for (int o = 32; o >= 1; o >>= 1) ss += __shfl_xor(ss, o, 64);
  if (lane == 0) inv[gr] = 1.0f / fmaxf(sqrtf(ss), 1e-12f);
}

// ---------------- bf16 2D transpose (sf only, proven) ----------------
__global__ __launch_bounds__(256) void transpose_k(const short* __restrict__ in, short* __restrict__ out,
                                                   int R, int C) {
  __shared__ short t[32][33];
  long base = (long)blockIdx.z * R * C;
  int c0 = blockIdx.x * 32, r0 = blockIdx.y * 32;
  int tx = threadIdx.x & 31, ty = threadIdx.x >> 5;
  #pragma unroll
  for (int i = 0; i < 32; i += 8)
    t[ty + i][tx] = in[base + (long)(r0 + ty + i) * C + c0 + tx];
  __syncthreads();
  #pragma unroll
  for (int i = 0; i < 32; i += 8)
    out[base + (long)(c0 + ty + i) * R + r0 + tx] = t[tx][ty + i];
}

// ---------------- merged af+sa permute+transpose + fused sumsq atomics ----------------
__global__ __launch_bounds__(256) void permtr_all_k(const float* __restrict__ x,
    short* __restrict__ Qaf, short* __restrict__ QTaf,
    short* __restrict__ Qsa, short* __restrict__ QTsa,
    float* __restrict__ ssaf, float* __restrict__ sssa) {
  __shared__ short t[32][33];
  int bid = blockIdx.x;
  int isAF = (bid < 17280);
  int M, Mp, Kp, kt, mt, b;
  short *Q, *QT; float* ss;
  if (isAF) { M = 320; Mp = 384; Kp = 11520; kt = bid % 360; int r = bid / 360; mt = r % 12; b = r / 12;
              Q = Qaf; QT = QTaf; ss = ssaf; }
  else { int id = bid - 17280; M = 240; Mp = 256; Kp = 15360; kt = id % 480; int r = id / 480; mt = r % 8; b = r / 8;
         Q = Qsa; QT = QTsa; ss = sssa; }
  int k0 = kt * 32, m0 = mt * 32;
  int tx = threadIdx.x & 31, ty = threadIdx.x >> 5;
  const float* xb = x + (long)b * 3686400;
  #pragma unroll
  for (int i = 0; i < 32; i += 8) {
    int m = m0 + ty + i, k = k0 + tx;
    float v = 0.f;
    if (m < M) {
      int q1 = k / 240, r2 = k - q1 * 240;
      int v5 = r2 / 48, wv = r2 - v5 * 48;
      int a1 = m / 5, u = m - a1 * 5;
      long xi = isAF ? ((long)a1 * 25 + u * 5 + v5) * 2304 + q1 * 48 + wv
                     : ((long)q1 * 25 + u * 5 + v5) * 2304 + a1 * 48 + wv;
      v = xb[xi];
    }
    t[ty + i][tx] = f2b(v);
  }
  __syncthreads();
  long Qb = (long)b * Mp * Kp;
  #pragma unroll
  for (int i = 0; i < 32; i += 8)
    Q[Qb + (long)(m0 + ty + i) * Kp + k0 + tx] = t[ty + i][tx];
  #pragma unroll
  for (int i = 0; i < 32; i += 8)
    QT[Qb + (long)(k0 + ty + i) * Mp + m0 + tx] = t[tx][ty + i];
  if (threadIdx.x < 32 && m0 + (int)threadIdx.x < M) {
    float s = 0.f;
    #pragma unroll
    for (int k = 0; k < 32; ++k) { float f = b2f(t[threadIdx.x][k]); s += f * f; }
    atomicAdd(&ss[b * Mp + m0 + threadIdx.x], s);
  }
}

// ---------------- sf GEMM1: triangular, BK=64 2-phase dbuf; P=exp(cos)+rowsums --------
// round-13: + bijective XCD swizzle (300 = 8*37+4)
__global__ __launch_bounds__(256, 2) void gemm1_tri_k(const short* __restrict__ Q,
                                                      const float* __restrict__ invn,
                                                      short* __restrict__ att,
                                                      float* __restrict__ rowsum) {
  __shared__ short sm[32768];
  int tid = threadIdx.x, wave = tid >> 6, lane = tid & 63;
  int la = lane & 15, lb = lane >> 4;
  int bat = blockIdx.z;
  int bx;
  { int xcd = blockIdx.x & 7, j = blockIdx.x >> 3;
    bx = (xcd < 4) ? xcd * 38 + j : 152 + (xcd - 4) * 37 + j; }
  int yt = 0, rem = bx;
  while (rem >= 24 - yt) { rem -= 24 - yt; ++yt; }
  int xt = yt + rem;
  const short* Qb = Q + (long)bat * 3932160L;
  const float* inv = invn + (long)bat * 3072;
  int row0 = yt * 128, col0 = xt * 128;
  f32x4 acc[4][4] = {};
  int wr = wave >> 1, wc = wave & 1;
  int rloc = tid >> 3, cbase = (tid & 7) * 8;
  int ldsoff = tid * 8;

  const short *pA[4], *pB[4];
  #pragma unroll
  for (int p = 0; p < 4; ++p) {
    int row = p * 32 + rloc;
    int sc = SWZ(row, cbase);
    pA[p] = Qb + (long)(row0 + row) * 1280 + sc;
    pB[p] = Qb + (long)(col0 + row) * 1280 + sc;
  }

  #define TRI_STAGE(KT, BUF) { \
    short* Asb = sm + (BUF) * 16384; \
    short* Bsb = Asb + 8192; \
    _Pragma("unroll") \
    for (int p = 0; p < 4; ++p) { \
      gload16(pA[p] + (KT) * 64, (void*)(Asb + p * 2048 + ldsoff)); \
      gload16(pB[p] + (KT) * 64, (void*)(Bsb + p * 2048 + ldsoff)); \
    } }
  #define TRI_COMP(BUF) { \
    const short* Asb = sm + (BUF) * 16384; \
    const short* Bsb = Asb + 8192; \
    _Pragma("unroll") \
    for (int kk = 0; kk < 64; kk += 32) { \
      bf16x8 av[4], bv[4]; \
      _Pragma("unroll") \
      for (int m = 0; m < 4; ++m) \
        av[m] = *(const bf16x8*)&Asb[(wr * 64 + m * 16 + la) * 64 + SWZ(la, kk + lb * 8)]; \
      _Pragma("unroll") \
      for (int nn = 0; nn < 4; ++nn) \
        bv[nn] = *(const bf16x8*)&Bsb[(wc * 64 + nn * 16 + la) * 64 + SWZ(la, kk + lb * 8)]; \
      _Pragma("unroll") \
      for (int m = 0; m < 4; ++m) \
        _Pragma("unroll") \
        for (int nn = 0; nn < 4; ++nn) \
          acc[m][nn] = __builtin_amdgcn_mfma_f32_16x16x32_bf16(av[m], bv[nn], acc[m][nn], 0, 0, 0); \
    } }

  TRI_STAGE(0, 0)
  for (int kt = 0; kt < 19; ++kt) {
    TRI_STAGE(kt + 1, (kt + 1) & 1)
    asm volatile("s_waitcnt vmcnt(8)" ::: "memory");
    __builtin_amdgcn_s_barrier();
    TRI_COMP(kt & 1)
    asm volatile("" ::: "memory");
    __builtin_amdgcn_s_barrier();
  }
  asm volatile("s_waitcnt vmcnt(0)" ::: "memory");
  __builtin_amdgcn_s_barrier();
  TRI_COMP(1)
  asm volatile("" ::: "memory");
  __builtin_amdgcn_s_barrier();

  short* staged = sm;
  #pragma unroll
  for (int m = 0; m < 4; ++m) {
    #pragma unroll
    for (int nn = 0; nn < 4; ++nn) {
      int cl = wc * 64 + nn * 16 + la;
      float ic = inv[col0 + cl];
      #pragma unroll
      for (int j = 0; j < 4; ++j) {
        int rl = wr * 64 + m * 16 + lb * 4 + j;
        staged[rl * 136 + cl] = f2b(__expf(acc[m][nn][j] * inv[row0 + rl] * ic));
      }
    }
  }
  __syncthreads();
  short* attb = att + (long)bat * 9437184L;
  float* rsb = rowsum + (long)bat * 3072;
  {
    int r = tid >> 1, half = tid & 1;
    short* dst = attb + (long)(row0 + r) * 3072 + col0 + half * 64;
    const short* src = &staged[r * 136 + half * 64];
    float s = 0.f;
    #pragma unroll
    for (int q = 0; q < 8; ++q) {
      bf16x8 v = *(const bf16x8*)&src[q * 8];
      *(bf16x8*)&dst[q * 8] = v;
      #pragma unroll
      for (int jj = 0; jj < 8; ++jj) s += b2f(v[jj]);
    }
    s += __shfl_xor(s, 1, 64);
    if (half == 0) atomicAdd(&rsb[row0 + r], s);
  }
  if (xt != yt) {
    int c = tid >> 1, half = tid & 1;
    short* dst = attb + (long)(col0 + c) * 3072 + row0 + half * 64;
    float s = 0.f;
    #pragma unroll
    for (int q = 0; q < 8; ++q) {
      bf16x8 o;
      #pragma unroll
      for (int jj = 0; jj < 8; ++jj) {
        o[jj] = staged[(half * 64 + q * 8 + jj) * 136 + c];
        s += b2f(o[jj]);
      }
      *(bf16x8*)&dst[q * 8] = o;
    }
    s += __shfl_xor(s, 1, 64);
    if (half == 0) atomicAdd(&rsb[col0 + c], s);
  }
}

// ---------------- merged af+sa GEMM1: raw f32 S, split-K atomics, BK=64 dbuf ----------
__global__ __launch_bounds__(256, 2) void gemm_s_all_k(
    const short* __restrict__ Aaf, const short* __restrict__ Asa,
    float* __restrict__ Sfaf, float* __restrict__ Sfsa)
{
  __shared__ short sm[32768];
  int bid = blockIdx.x;
  const short* A; float* Sf;
  int lda, ktotal, ksper, ldc, row0, col0, bat, kc;
  long sA, sS;
  if (bid < 288) {
    int txy = bid % 9, z = bid / 9;
    col0 = (txy % 3) * 128; row0 = (txy / 3) * 128;
    bat = z / 8; kc = z % 8;
    lda = 11520; ktotal = 180; ksper = 23; ldc = 384;
    sA = 4423680L; sS = 147456L; A = Aaf; Sf = Sfaf;
  } else {
    int id = bid - 288;
    int txy = id % 4, z = id / 4;
    col0 = (txy % 2) * 128; row0 = (txy / 2) * 128;
    bat = z / 16; kc = z % 16;
    lda = 15360; ktotal = 240; ksper = 15; ldc = 256;
    sA = 3932160L; sS = 65536L; A = Asa; Sf = Sfsa;
  }
  int tid = threadIdx.x;
  int wave = tid >> 6, lane = tid & 63;
  int la = lane & 15, lb = lane >> 4;
  const short* Ab = A + (long)bat * sA;
  int kb = kc * ksper, ke = min(ktotal, kb + ksper);
  int L = ke - kb;
  f32x4 acc[4][4] = {};
  int wr = wave >> 1, wc = wave & 1;
  int rloc = tid >> 3, cbase = (tid & 7) * 8;
  int ldsoff = tid * 8;

  const short *pA[4], *pB[4];
  #pragma unroll
  for (int p = 0; p < 4; ++p) {
    int row = p * 32 + rloc;
    int sc = SWZ(row, cbase);
    pA[p] = Ab + (long)(row0 + row) * lda + sc;
    pB[p] = Ab + (long)(col0 + row) * lda + sc;
  }

  #define GS_STAGE(KT, BUF) { \
    short* Asb = sm + (BUF) * 16384; \
    short* Bsb = Asb + 8192; \
    _Pragma("unroll") \
    for (int p = 0; p < 4; ++p) { \
      gload16(pA[p] + (KT) * 64, (void*)(Asb + p * 2048 + ldsoff)); \
      gload16(pB[p] + (KT) * 64, (void*)(Bsb + p * 2048 + ldsoff)); \
    } }
  #define GS_COMP(BUF) { \
    const short* Asb = sm + (BUF) * 16384; \
    const short* Bsb = Asb + 8192; \
    _Pragma("unroll") \
    for (int kk = 0; kk < 64; kk += 32) { \
      bf16x8 av[4], bv[4]; \
      _Pragma("unroll") \
      for (int m = 0; m < 4; ++m) \
        av[m] = *(const bf16x8*)&Asb[(wr * 64 + m * 16 + la) * 64 + SWZ(la, kk + lb * 8)]; \
      _Pragma("unroll") \
      for (int nn = 0; nn < 4; ++nn) \
        bv[nn] = *(const bf16x8*)&Bsb[(wc * 64 + nn * 16 + la) * 64 + SWZ(la, kk + lb * 8)]; \
      _Pragma("unroll") \
      for (int m = 0; m < 4; ++m) \
        _Pragma("unroll") \
        for (int nn = 0; nn < 4; ++nn) \
          acc[m][nn] = __builtin_amdgcn_mfma_f32_16x16x32_bf16(av[m], bv[nn], acc[m][nn], 0, 0, 0); \
    } }

  GS_STAGE(kb, 0)
  for (int t = 0; t < L - 1; ++t) {
    GS_STAGE(kb + t + 1, (t + 1) & 1)
    asm volatile("s_waitcnt vmcnt(8)" ::: "memory");
    __builtin_amdgcn_s_barrier();
    GS_COMP(t & 1)
    asm volatile("" ::: "memory");
    __builtin_amdgcn_s_barrier();
  }
  asm volatile("s_waitcnt vmcnt(0)" ::: "memory");
  __builtin_amdgcn_s_barrier();
  GS_COMP((L - 1) & 1)

  float* Sb = Sf + (long)bat * sS;
  #pragma unroll
  for (int m = 0; m < 4; ++m) {
    int gr0 = row0 + wr * 64 + m * 16 + lb * 4;
    #pragma unroll
    for (int nn = 0; nn < 4; ++nn) {
      int gc = col0 + wc * 64 + nn * 16 + la;
      #pragma unroll
      for (int j = 0; j < 4; ++j)
        atomicAdd(&Sb[(long)(gr0 + j) * ldc + gc], acc[m][nn][j]);
    }
  }
}

// ---------------- merged af+sa softmax: row-per-wave, in-register ----------------
__global__ __launch_bounds__(256) void softmax_all_k(
    const float* __restrict__ Sfaf, const float* __restrict__ Sfsa,
    const float* __restrict__ ssaf, const float* __restrict__ sssa,
    short* __restrict__ attaf, short* __restrict__ attsa)
{
  int wave = threadIdx.x >> 6, lane = threadIdx.x & 63;
  int rid = blockIdx.x * 4 + wave;
  int row, b, Mv, Mp; const float *Sf, *ss; short* att;
  if (rid < 1280) { row = rid % 320; b = rid / 320; Mv = 320; Mp = 384; Sf = Sfaf; ss = ssaf; att = attaf; }
  else { int id = rid - 1280; row = id % 240; b = id / 240; Mv = 240; Mp = 256; Sf = Sfsa; ss = sssa; att = attsa; }
  long sS = (long)Mp * Mp;
  const float* Sr = Sf + (long)b * sS + (long)row * Mp;
  const float* ssb = ss + b * Mp;
  float inv_i = rsqrtf(fmaxf(ssb[row], 1e-24f));
  float ev[6] = {0.f, 0.f, 0.f, 0.f, 0.f, 0.f};
  float sum = 0.f;
  #pragma unroll
  for (int q = 0; q < 6; ++q) {
    int j = q * 64 + lane;
    if (j < Mv) {
      float e = __expf(Sr[j] * inv_i * rsqrtf(fmaxf(ssb[j], 1e-24f)));
      ev[q] = e; sum += e;
    }
  }
  #pragma unroll
  for (int o = 32; o >= 1; o >>= 1) sum += __shfl_xor(sum, o, 64);
  float rden = 1.0f / sum;
  short* ar = att + (long)b * sS + (long)row * Mp;
  #pragma unroll
  for (int q = 0; q < 6; ++q) {
    int j = q * 64 + lane;
    if (j < Mp) ar[j] = (j < Mv) ? f2b(ev[q] * rden) : (short)0;
  }
}

// ---------------- sf GEMM2: 256x256 tile, 8 waves, 4-phase counted-vmcnt dbuf ----------
__global__ __launch_bounds__(512) void gemm2sf_k(const short* __restrict__ A,
                                                 const short* __restrict__ B,
                                                 const float* __restrict__ rowsum,
                                                 short* __restrict__ F) {
  __shared__ short sm[65536];
  int tid = threadIdx.x;
  int wave = tid >> 6, lane = tid & 63;
  int la = lane & 15, lb = lane >> 4;
  int wr = wave >> 2, wc = wave & 3;
  int wk;
  { int xcd = blockIdx.x & 7, j = blockIdx.x >> 3; wk = xcd * 30 + j; }
  int yt = wk % 12, rem = wk / 12;
  int xt = rem % 5, bat = rem / 5;
  const short* Ab = A + (long)bat * 9437184L;
  const short* Bb = B + (long)bat * 3932160L;
  int rloc = tid >> 3;
  int cbase = (tid & 7) * 8;
  int sc = cbase ^ ((rloc & 7) << 3);
  const short *pAg[4], *pBg[4];
  #pragma unroll
  for (int g = 0; g < 4; ++g) {
    pAg[g] = Ab + (long)(rloc * 48 + yt * 4 + g) * 3072 + sc;
    pBg[g] = Bb + (long)(xt * 256 + g * 64 + rloc) * 3072 + sc;
  }
  f32x4 acc[8][4] = {};

  #pragma unroll
  for (int g = 0; g < 4; ++g) {
    gload16(pAg[g], (void*)(sm + g * 4096 + tid * 8));
    gload16(pBg[g], (void*)(sm + 16384 + g * 4096 + tid * 8));
  }
  asm volatile("s_waitcnt vmcnt(0)" ::: "memory");
  __builtin_amdgcn_s_barrier();

  #define G2_PHASE(MH, KK, LOADB) { \
    if (LOADB) { \
      _Pragma("unroll") \
      for (int nn = 0; nn < 4; ++nn) \
        bv[nn] = *(const bf16x8*)&Bsb[(wc * 64 + nn * 16 + la) * 64 + SWZ(la, (KK) + lb * 8)]; \
    } \
    _Pragma("unroll") \
    for (int m = 0; m < 4; ++m) \
      av[m] = *(const bf16x8*)&Asb[(wr * 128 + (MH) * 64 + m * 16 + la) * 64 + SWZ(la, (KK) + lb * 8)]; \
    __builtin_amdgcn_s_setprio(1); \
    _Pragma("unroll") \
    for (int m = 0; m < 4; ++m) \
      _Pragma("unroll") \
      for (int nn = 0; nn < 4; ++nn) \
        acc[(MH) * 4 + m][nn] = __builtin_amdgcn_mfma_f32_16x16x32_bf16(av[m], bv[nn], acc[(MH) * 4 + m][nn], 0, 0, 0); \
    __builtin_amdgcn_s_setprio(0); \
  }

  for (int t = 0; t < 48; ++t) {
    const short* Asb = sm + (t & 1) * 32768;
    const short* Bsb = Asb + 16384;
    short* An = sm + ((t + 1) & 1) * 32768;
    short* Bn = An + 16384;
    int k1 = (t + 1) * 64;
    bool pf = (t < 47);
    bf16x8 av[4], bv[4];

    asm volatile("s_waitcnt vmcnt(2)" ::: "memory");
    __builtin_amdgcn_s_barrier();
    if (pf) { gload16(pBg[0] + k1, (void*)(Bn + tid * 8));
              gload16(pBg[1] + k1, (void*)(Bn + 4096 + tid * 8)); }
    G2_PHASE(0, 0, 1)
    if (pf) asm volatile("s_waitcnt vmcnt(2)" ::: "memory");
    else    asm volatile("s_waitcnt vmcnt(0)" ::: "memory");
    __builtin_amdgcn_s_barrier();
    if (pf) { gload16(pBg[2] + k1, (void*)(Bn + 8192 + tid * 8));
              gload16(pBg[3] + k1, (void*)(Bn + 12288 + tid * 8)); }
    G2_PHASE(1, 0, 0)
    asm volatile("s_waitcnt vmcnt(4)" ::: "memory");
    __builtin_amdgcn_s_barrier();
    if (pf) { gload16(pAg[0] + k1, (void*)(An + tid * 8));
              gload16(pAg[2] + k1, (void*)(An + 8192 + tid * 8)); }
    G2_PHASE(0, 32, 1)
    asm volatile("s_waitcnt vmcnt(6)" ::: "memory");
    __builtin_amdgcn_s_barrier();
    if (pf) { gload16(pAg[1] + k1, (void*)(An + 4096 + tid * 8));
              gload16(pAg[3] + k1, (void*)(An + 12288 + tid * 8)); }
    G2_PHASE(1, 32, 0)
  }
  __syncthreads();

  const float* rsb = rowsum + (long)bat * 3072;
  float rs[8][4];
  #pragma unroll
  for (int m = 0; m < 8; ++m) {
    int sub = wr * 2 + (m >> 2);
    #pragma unroll
    for (int j = 0; j < 4; ++j) {
      int cc = (m & 3) * 16 + lb * 4 + j;
      rs[m][j] = 1.0f / rsb[cc * 48 + yt * 4 + sub];
    }
  }
  short* staged = sm;
  #pragma unroll
  for (int m = 0; m < 8; ++m) {
    int sub = wr * 2 + (m >> 2);
    #pragma unroll
    for (int nn = 0; nn < 4; ++nn) {
      int gcl = wc * 64 + nn * 16 + la;
      int chunk = gcl * 4 + sub;
      int key = (gcl & 7) << 3;
      short4 o;
      o.x = f2b(acc[m][nn][0] * rs[m][0]); o.y = f2b(acc[m][nn][1] * rs[m][1]);
      o.z = f2b(acc[m][nn][2] * rs[m][2]); o.w = f2b(acc[m][nn][3] * rs[m][3]);
      *(short4*)&staged[chunk * 64 + (((m & 3) * 16 + lb * 4) ^ key)] = o;
    }
  }
  __syncthreads();
  #pragma unroll
  for (int i = 0; i < 16; ++i) {
    int chunk = i * 64 + (tid >> 3);
    int part = tid & 7;
    int gcl = chunk >> 2, sub = chunk & 3;
    int key = (gcl & 7) << 3;
    bf16x8 v = *(const bf16x8*)&staged[chunk * 64 + ((part * 8) ^ key)];
    int gc = xt * 256 + gcl;
    if (gc < 1200) {
      int hh = yt * 4 + sub;
      int wv = gc / 25, nidx = gc - wv * 25;
      long base = (((long)(bat * 48 + hh) * 48 + wv) * 25 + nidx) * 192 + part * 8;
      *(bf16x8*)&F[base] = v;
    }
  }
}

// ---------------- merged af+sa GEMM2 (1-phase) with XCD swizzle ----------------
__global__ __launch_bounds__(256) void gemm2_afsa_k(
    const short* __restrict__ attaf, const short* __restrict__ QTaf,
    const short* __restrict__ attsa, const short* __restrict__ QTsa,
    short* __restrict__ F)
{
  __shared__ short sm[20480];
  short* As = sm;
  short* Bs = sm + 4096;
  int bid = blockIdx.x;
  int isAF = (bid < 900);
  int NX, NY, LDA, KST, wk;
  const short *A, *B; long SA, SB;
  if (isAF) {
    NX = 45; NY = 5; LDA = 384; KST = 6; SA = 147456L; SB = 4423680L; A = attaf; B = QTaf;
    int xcd = bid & 7, j = bid >> 3;
    wk = (xcd < 4) ? xcd * 113 + j : 4 * 113 + (xcd - 4) * 112 + j;
  } else {
    NX = 60; NY = 4; LDA = 256; KST = 4; SA = 65536L; SB = 3932160L; A = attsa; B = QTsa;
    int id = bid - 900;
    int xcd = id & 7, j = id >> 3;
    wk = xcd * 120 + j;
  }
  int yt = wk % NY, rem = wk / NY;
  int xt = rem % NX, bat = rem / NX;
  int tid = threadIdx.x, wave = tid >> 6, lane = tid & 63;
  int la = lane & 15, lb = lane >> 4;
  const short* Ab = A + (long)bat * SA;
  const short* Bb = B + (long)bat * SB;
  f32x4 acc[4][4] = {};
  int rloc = tid >> 3, cbase = (tid & 7) * 8;
  int ldsoff = tid * 8;

  const short *pA[2], *pB[8];
  #pragma unroll
  for (int p = 0; p < 2; ++p) {
    int r = p * 32 + rloc;
    int sc = SWZ(r, cbase);
    int rowg = isAF ? (r * 5 + yt) : (yt * 64 + r);
    pA[p] = Ab + (long)rowg * LDA + sc;
  }
  #pragma unroll
  for (int p = 0; p < 8; ++p) {
    int rb = p * 32 + rloc;
    int sc = SWZ(rb, cbase);
    int rowg;
    if (isAF) rowg = xt * 256 + rb;
    else { int c = rb & 63, g = rb >> 6; rowg = c * 240 + xt * 4 + g; }
    pB[p] = Bb + (long)rowg * LDA + sc;
  }

  for (int kt = 0; kt < KST; ++kt) {
    #pragma unroll
    for (int p = 0; p < 2; ++p)
      gload16(pA[p] + kt * 64, (void*)(As + p * 2048 + ldsoff));
    #pragma unroll
    for (int p = 0; p < 8; ++p)
      gload16(pB[p] + kt * 64, (void*)(Bs + p * 2048 + ldsoff));
    __syncthreads();
    #pragma unroll
    for (int kk = 0; kk < 64; kk += 32) {
      bf16x8 av[4], bv[4];
      #pragma unroll
      for (int m = 0; m < 4; ++m)
        av[m] = *(const bf16x8*)&As[(m * 16 + la) * 64 + SWZ(la, kk + lb * 8)];
      #pragma unroll
      for (int nn = 0; nn < 4; ++nn)
        bv[nn] = *(const bf16x8*)&Bs[(wave * 64 + nn * 16 + la) * 64 + SWZ(la, kk + lb * 8)];
      #pragma unroll
      for (int m = 0; m < 4; ++m)
        #pragma unroll
        for (int nn = 0; nn < 4; ++nn)
          acc[m][nn] = __builtin_amdgcn_mfma_f32_16x16x32_bf16(av[m], bv[nn], acc[m][nn], 0, 0, 0);
    }
    __syncthreads();
  }

  short* staged = sm;
  #pragma unroll
  for (int m = 0; m < 4; ++m) {
    #pragma unroll
    for (int nn = 0; nn < 4; ++nn) {
      if (!isAF) {
        #pragma unroll
        for (int j = 0; j < 4; ++j)
          staged[((m * 16 + lb * 4 + j) * 4 + wave) * 72 + nn * 16 + la] = f2b(acc[m][nn][j]);
      } else {
        short4 o;
        o.x = f2b(acc[m][nn][0]); o.y = f2b(acc[m][nn][1]);
        o.z = f2b(acc[m][nn][2]); o.w = f2b(acc[m][nn][3]);
        *(short4*)&staged[(wave * 64 + nn * 16 + la) * 72 + m * 16 + lb * 4] = o;
      }
    }
  }
  __syncthreads();

  #pragma unroll
  for (int rd = 0; rd < 8; ++rd) {
    int chunk = rd * 32 + (tid >> 3);
    int part = tid & 7;
    bf16x8 v = *(const bf16x8*)&staged[chunk * 72 + part * 8];
    long base; bool ok = true;
    if (isAF) {
      int gc = xt * 256 + chunk;
      int hh = gc / 240, r2 = gc - hh * 240, v5 = r2 / 48, wv = r2 - v5 * 48;
      base = (((long)(bat * 48 + hh) * 48 + wv) * 25 + yt * 5 + v5) * 192 + 64 + part * 8;
    } else {
      int r = chunk >> 2, g = chunk & 3;
      int gr = yt * 64 + r; ok = (gr < 240);
      int hh = gr / 5, u = gr - hh * 5;
      int r2 = xt * 4 + g, v5 = r2 / 48, wv = r2 - v5 * 48;
      base = (((long)(bat * 48 + hh) * 48 + wv) * 25 + u * 5 + v5) * 192 + 128 + part * 8;
    }
    if (ok) *(bf16x8*)&F[base] = v;
  }
}

// ---------------- weight prep ----------------
__global__ __launch_bounds__(256) void prep_w_k(const float* __restrict__ w1, const float* __restrict__ w2,
                                                short* __restrict__ w1t, short* __restrict__ w2t) {
  int idx = blockIdx.x * 256 + threadIdx.x;
  if (idx < 12288) {
    int i = idx / 64, j = idx - i * 64;
    w1t[j * 192 + i] = f2b(w1[idx]);
  } else if (idx < 16384) {
    int k = idx - 12288;
    int i = k / 64, j = k - i * 64;
    w2t[j * 64 + i] = f2b(w2[k]);
  }
}

// ---------------- fused (+x) LayerNorm + MFMA MLP + residual ----------------
__global__ __launch_bounds__(256) void ln_mlp_mfma_k(
    const short* __restrict__ F, const float* __restrict__ x,
    const float* __restrict__ gamma, const float* __restrict__ beta,
    const short* __restrict__ w1t, const short* __restrict__ w2t,
    float* __restrict__ out)
{
  int n = blockIdx.x, hh = blockIdx.y, b = blockIdx.z;
  __shared__ short A1[48 * 200];
  __shared__ float xs[64 * 49];
  __shared__ __align__(16) char pool[19584];
  short* Fs = (short*)pool;
  short* Y1 = (short*)pool;
  float* Y2 = (float*)(pool + 6912);
  int tid = threadIdx.x, wave = tid >> 6, lane = tid & 63;
  int la = lane & 15, lb = lane >> 4;
  long Fb0 = ((long)(b * 48 + hh) * 1200 + n) * 192;
  long xb = (long)b * 3686400 + (long)n * 2304 + hh * 48;

  #pragma unroll
  for (int it = 0; it < 5; ++it) {
    int ci = tid + 256 * it;
    if (ci < 1152) {
      int r = ci / 24, q = ci - r * 24;
      gload16(&F[Fb0 + (long)r * 4800 + q * 8], (void*)(Fs + ci * 8));
    }
  }
  {
    int ch = tid >> 2, qq = tid & 3;
    const float* xr = x + xb + (long)ch * 57600 + qq * 12;
    #pragma unroll
    for (int i = 0; i < 12; ++i) xs[ch * 49 + qq * 12 + i] = xr[i];
  }
  __syncthreads();

  float g0 = gamma[lane], g1 = gamma[lane + 64], g2 = gamma[lane + 128];
  float bt0 = beta[lane], bt1 = beta[lane + 64], bt2 = beta[lane + 128];
  #pragma unroll 4
  for (int rr = 0; rr < 12; ++rr) {
    int r = wave * 12 + rr;
    float xv = xs[lane * 49 + r];
    float v0 = b2f(Fs[r * 192 + lane]) + xv;
    float v1 = b2f(Fs[r * 192 + lane + 64]) + xv;
    float v2 = b2f(Fs[r * 192 + lane + 128]) + xv;
    float s = v0 + v1 + v2;
    #pragma unroll
    for (int o = 32; o >= 1; o >>= 1) s += __shfl_xor(s, o, 64);
    float mu = s * (1.f / 192.f);
    float d0 = v0 - mu, d1 = v1 - mu, d2 = v2 - mu;
    float q = d0 * d0 + d1 * d1 + d2 * d2;
    #pragma unroll
    for (int o = 32; o >= 1; o >>= 1) q += __shfl_xor(q, o, 64);
    float rsq = rsqrtf(q * (1.f / 192.f) + 1e-5f);
    A1[r * 200 + lane]       = f2b(d0 * rsq * g0 + bt0);
    A1[r * 200 + lane + 64]  = f2b(d1 * rsq * g1 + bt1);
    A1[r * 200 + lane + 128] = f2b(d2 * rsq * g2 + bt2);
  }
  __syncthreads();

  f32x4 acc1[3] = {};
  #pragma unroll
  for (int ks = 0; ks < 6; ++ks) {
    bf16x8 bv = *(const bf16x8*)&w1t[(wave * 16 + la) * 192 + ks * 32 + lb * 8];
    #pragma unroll
    for (int m = 0; m < 3; ++m) {
      bf16x8 av = *(const bf16x8*)&A1[(m * 16 + la) * 200 + ks * 32 + lb * 8];
      acc1[m] = __builtin_amdgcn_mfma_f32_16x16x32_bf16(av, bv, acc1[m], 0, 0, 0);
    }
  }
  #pragma unroll
  for (int m = 0; m < 3; ++m)
    #pragma unroll
    for (int j = 0; j < 4; ++j)
      Y1[(m * 16 + lb * 4 + j) * 72 + wave * 16 + la] = f2b(fmaxf(acc1[m][j], 0.f));
  __syncthreads();

  f32x4 acc2[3] = {};
  #pragma unroll
  for (int ks = 0; ks < 2; ++ks) {
    bf16x8 bv = *(const bf16x8*)&w2t[(wave * 16 + la) * 64 + ks * 32 + lb * 8];
    #pragma unroll
    for (int m = 0; m < 3; ++m) {
      bf16x8 av = *(const bf16x8*)&Y1[(m * 16 + la) * 72 + ks * 32 + lb * 8];
      acc2[m] = __builtin_amdgcn_mfma_f32_16x16x32_bf16(av, bv, acc2[m], 0, 0, 0);
    }
  }
  #pragma unroll
  for (int m = 0; m < 3; ++m)
    #pragma unroll
    for (int j = 0; j < 4; ++j)
      Y2[(m * 16 + lb * 4 + j) * 66 + wave * 16 + la] = acc2[m][j];
  __syncthreads();

  #pragma unroll
  for (int i = 0; i < 12; ++i) {
    int e = tid + 256 * i;
    int cc = e / 48, wv = e - cc * 48;
    out[xb + (long)cc * 57600 + wv] = Y2[wv * 66 + cc] + xs[cc * 49 + wv];
  }
}

// ---------------- host launcher ----------------
extern "C" void kernel_launch(void* const* d_in, const int* in_sizes, int n_in,
                              void* d_out, int out_size, void* d_ws, size_t ws_size,
                              hipStream_t stream) {
  (void)in_sizes; (void)n_in; (void)out_size;
  const float* x     = (const float*)d_in[0];
  const float* gamma = (const float*)d_in[1];
  const float* beta  = (const float*)d_in[2];
  const float* w1    = (const float*)d_in[3];
  const float* w2    = (const float*)d_in[4];
  float* out = (float*)d_out;

  const size_t NEED = 237191168UL;
  if (ws_size < NEED) return;
  char* ws = (char*)d_ws;
  short* F     = (short*)(ws);
  short* attsf = (short*)(ws + 88473600UL);
  short* Qsf   = (short*)(ws + 163971072UL);
  short* QTsf  = (short*)(ws + 199360512UL);
  float* rowsum = (float*)(ws + 234749952UL);
  float* invn  = (float*)(ws + 237109248UL);
  short* w1t   = (short*)(ws + 237158400UL);
  short* w2t   = (short*)(ws + 237182976UL);
  // phase 2 (af+sa) reuses sf regions
  short* Qaf   = (short*)(ws + 88473600UL);
  short* QTaf  = (short*)(ws + 123863040UL);
  float* Sfsa  = (float*)(ws + 159252480UL);
  float* ssaf  = (float*)(ws + 160301056UL);
  float* sssa  = (float*)(ws + 160307200UL);
  short* attaf = (short*)(ws + 160311296UL);
  short* attsa = (short*)(ws + 161490944UL);
  short* Qsa   = (short*)(ws + 163971072UL);
  short* QTsa  = (short*)(ws + 195428352UL);
  float* Sfaf  = (float*)(ws + 234749952UL);

  prep_w_k<<<64, 256, 0, stream>>>(w1, w2, w1t, w2t);

  // ================= SF =================
  permute_sf_k<<<3072, 256, 0, stream>>>(x, Qsf, invn);
  transpose_k<<<dim3(40, 96, 4), 256, 0, stream>>>(Qsf, QTsf, 3072, 1280);
  hipMemsetAsync(rowsum, 0, 49152, stream);
  gemm1_tri_k<<<dim3(300, 1, 4), 256, 0, stream>>>(Qsf, invn, attsf, rowsum);
  gemm2sf_k<<<dim3(240), 512, 0, stream>>>(attsf, QTsf, rowsum, F);

  // ================= AF + SA merged =================
  hipMemsetAsync(Sfaf, 0, 2359296, stream);
  hipMemsetAsync((char*)Sfsa, 0, 1058816, stream);   // Sfsa + ssaf + sssa (contiguous)
  permtr_all_k<<<32640, 256, 0, stream>>>(x, Qaf, QTaf, Qsa, QTsa, ssaf, sssa);
  gemm_s_all_k<<<544, 256, 0, stream>>>(Qaf, Qsa, Sfaf, Sfsa);
  softmax_all_k<<<560, 256, 0, stream>>>(Sfaf, Sfsa, ssaf, sssa, attaf, attsa);
  gemm2_afsa_k<<<1860, 256, 0, stream>>>(attaf, QTaf, attsa, QTsa, F);

  // ================= LN + MLP + residual =================
  ln_mlp_mfma_k<<<dim3(25, 48, 4), 256, 0, stream>>>(F, x, gamma, beta, w1t, w2t, out);
}

// Round 14
// 464.996 us; speedup vs baseline: 1.0292x; 1.0033x over previous
//
#include <hip/hip_runtime.h>
#include <stdint.h>

typedef __attribute__((ext_vector_type(8))) short bf16x8;
typedef __attribute__((ext_vector_type(4))) float f32x4;

__device__ __forceinline__ float b2f(short s) {
  union { unsigned u; float f; } a; a.u = ((unsigned)(unsigned short)s) << 16; return a.f;
}
__device__ __forceinline__ short f2b(float f) {
  union { float f; unsigned u; } a; a.f = f;
  unsigned r = a.u + 0x7fffu + ((a.u >> 16) & 1u);
  return (short)(r >> 16);
}
__device__ __forceinline__ void gload16(const void* g, void* l) {
  __builtin_amdgcn_global_load_lds((__attribute__((address_space(1))) void*)g,
                                   (__attribute__((address_space(3))) void*)l, 16, 0, 0);
}

// LDS XOR swizzle (T2, rule-21 form)
#define SWZ(row, col) ((col) ^ (((row) & 7) << 3))

// ---------------- SF permute + fused row inv-norm (proven R11) ----------------
__global__ __launch_bounds__(256) void permute_sf_k(const float* __restrict__ x,
                                                    short* __restrict__ Q,
                                                    float* __restrict__ inv) {
  __shared__ float buf[4][1200];
  int wave = threadIdx.x >> 6, lane = threadIdx.x & 63;
  int gr = blockIdx.x * 4 + wave;
  int b = gr / 3072, m = gr - b * 3072;
  int c = m / 48, hh = m - c * 48;
  const float* xb = x + (long)(b * 64 + c) * 57600 + hh * 48;
  for (int uv = 0; uv < 25; ++uv)
    if (lane < 48) buf[wave][uv * 48 + lane] = xb[uv * 2304 + lane];
  __syncthreads();
  short* Qr = Q + (long)gr * 1280;
  float ss = 0.f;
  for (int k = lane; k < 1280; k += 64) {
    float v = 0.f;
    if (k < 1200) { int wv = k / 25, uv = k - wv * 25; v = buf[wave][uv * 48 + wv]; }
    ss += v * v;
    Qr[k] = f2b(v);
  }
  #pragma unroll
  for (int o = 32; o >= 1; o >>= 1) ss += __shfl_xor(ss, o, 64);
  if (lane == 0) inv[gr] = 1.0f / fmaxf(sqrtf(ss), 1e-12f);
}

// ---------------- bf16 2D transpose (sf only, proven) ----------------
__global__ __launch_bounds__(256) void transpose_k(const short* __restrict__ in, short* __restrict__ out,
                                                   int R, int C) {
  __shared__ short t[32][33];
  long base = (long)blockIdx.z * R * C;
  int c0 = blockIdx.x * 32, r0 = blockIdx.y * 32;
  int tx = threadIdx.x & 31, ty = threadIdx.x >> 5;
  #pragma unroll
  for (int i = 0; i < 32; i += 8)
    t[ty + i][tx] = in[base + (long)(r0 + ty + i) * C + c0 + tx];
  __syncthreads();
  #pragma unroll
  for (int i = 0; i < 32; i += 8)
    out[base + (long)(c0 + ty + i) * R + r0 + tx] = t[tx][ty + i];
}

// ---------------- merged af+sa permute+transpose + fused sumsq atomics ----------------
__global__ __launch_bounds__(256) void permtr_all_k(const float* __restrict__ x,
    short* __restrict__ Qaf, short* __restrict__ QTaf,
    short* __restrict__ Qsa, short* __restrict__ QTsa,
    float* __restrict__ ssaf, float* __restrict__ sssa) {
  __shared__ short t[32][33];
  int bid = blockIdx.x;
  int isAF = (bid < 17280);
  int M, Mp, Kp, kt, mt, b;
  short *Q, *QT; float* ss;
  if (isAF) { M = 320; Mp = 384; Kp = 11520; kt = bid % 360; int r = bid / 360; mt = r % 12; b = r / 12;
              Q = Qaf; QT = QTaf; ss = ssaf; }
  else { int id = bid - 17280; M = 240; Mp = 256; Kp = 15360; kt = id % 480; int r = id / 480; mt = r % 8; b = r / 8;
         Q = Qsa; QT = QTsa; ss = sssa; }
  int k0 = kt * 32, m0 = mt * 32;
  int tx = threadIdx.x & 31, ty = threadIdx.x >> 5;
  const float* xb = x + (long)b * 3686400;
  #pragma unroll
  for (int i = 0; i < 32; i += 8) {
    int m = m0 + ty + i, k = k0 + tx;
    float v = 0.f;
    if (m < M) {
      int q1 = k / 240, r2 = k - q1 * 240;
      int v5 = r2 / 48, wv = r2 - v5 * 48;
      int a1 = m / 5, u = m - a1 * 5;
      long xi = isAF ? ((long)a1 * 25 + u * 5 + v5) * 2304 + q1 * 48 + wv
                     : ((long)q1 * 25 + u * 5 + v5) * 2304 + a1 * 48 + wv;
      v = xb[xi];
    }
    t[ty + i][tx] = f2b(v);
  }
  __syncthreads();
  long Qb = (long)b * Mp * Kp;
  #pragma unroll
  for (int i = 0; i < 32; i += 8)
    Q[Qb + (long)(m0 + ty + i) * Kp + k0 + tx] = t[ty + i][tx];
  #pragma unroll
  for (int i = 0; i < 32; i += 8)
    QT[Qb + (long)(k0 + ty + i) * Mp + m0 + tx] = t[tx][ty + i];
  if (threadIdx.x < 32 && m0 + (int)threadIdx.x < M) {
    float s = 0.f;
    #pragma unroll
    for (int k = 0; k < 32; ++k) { float f = b2f(t[threadIdx.x][k]); s += f * f; }
    atomicAdd(&ss[b * Mp + m0 + threadIdx.x], s);
  }
}

// ---------------- sf GEMM1: triangular, BK=64 2-phase dbuf; P=exp(cos)+rowsums --------
// round-13: + bijective XCD swizzle (300 = 8*37+4)
__global__ __launch_bounds__(256, 2) void gemm1_tri_k(const short* __restrict__ Q,
                                                      const float* __restrict__ invn,
                                                      short* __restrict__ att,
                                                      float* __restrict__ rowsum) {
  __shared__ short sm[32768];
  int tid = threadIdx.x, wave = tid >> 6, lane = tid & 63;
  int la = lane & 15, lb = lane >> 4;
  int bat = blockIdx.z;
  int bx;
  { int xcd = blockIdx.x & 7, j = blockIdx.x >> 3;
    bx = (xcd < 4) ? xcd * 38 + j : 152 + (xcd - 4) * 37 + j; }
  int yt = 0, rem = bx;
  while (rem >= 24 - yt) { rem -= 24 - yt; ++yt; }
  int xt = yt + rem;
  const short* Qb = Q + (long)bat * 3932160L;
  const float* inv = invn + (long)bat * 3072;
  int row0 = yt * 128, col0 = xt * 128;
  f32x4 acc[4][4] = {};
  int wr = wave >> 1, wc = wave & 1;
  int rloc = tid >> 3, cbase = (tid & 7) * 8;
  int ldsoff = tid * 8;

  const short *pA[4], *pB[4];
  #pragma unroll
  for (int p = 0; p < 4; ++p) {
    int row = p * 32 + rloc;
    int sc = SWZ(row, cbase);
    pA[p] = Qb + (long)(row0 + row) * 1280 + sc;
    pB[p] = Qb + (long)(col0 + row) * 1280 + sc;
  }

  #define TRI_STAGE(KT, BUF) { \
    short* Asb = sm + (BUF) * 16384; \
    short* Bsb = Asb + 8192; \
    _Pragma("unroll") \
    for (int p = 0; p < 4; ++p) { \
      gload16(pA[p] + (KT) * 64, (void*)(Asb + p * 2048 + ldsoff)); \
      gload16(pB[p] + (KT) * 64, (void*)(Bsb + p * 2048 + ldsoff)); \
    } }
  #define TRI_COMP(BUF) { \
    const short* Asb = sm + (BUF) * 16384; \
    const short* Bsb = Asb + 8192; \
    _Pragma("unroll") \
    for (int kk = 0; kk < 64; kk += 32) { \
      bf16x8 av[4], bv[4]; \
      _Pragma("unroll") \
      for (int m = 0; m < 4; ++m) \
        av[m] = *(const bf16x8*)&Asb[(wr * 64 + m * 16 + la) * 64 + SWZ(la, kk + lb * 8)]; \
      _Pragma("unroll") \
      for (int nn = 0; nn < 4; ++nn) \
        bv[nn] = *(const bf16x8*)&Bsb[(wc * 64 + nn * 16 + la) * 64 + SWZ(la, kk + lb * 8)]; \
      _Pragma("unroll") \
      for (int m = 0; m < 4; ++m) \
        _Pragma("unroll") \
        for (int nn = 0; nn < 4; ++nn) \
          acc[m][nn] = __builtin_amdgcn_mfma_f32_16x16x32_bf16(av[m], bv[nn], acc[m][nn], 0, 0, 0); \
    } }

  TRI_STAGE(0, 0)
  for (int kt = 0; kt < 19; ++kt) {
    TRI_STAGE(kt + 1, (kt + 1) & 1)
    asm volatile("s_waitcnt vmcnt(8)" ::: "memory");
    __builtin_amdgcn_s_barrier();
    TRI_COMP(kt & 1)
    asm volatile("" ::: "memory");
    __builtin_amdgcn_s_barrier();
  }
  asm volatile("s_waitcnt vmcnt(0)" ::: "memory");
  __builtin_amdgcn_s_barrier();
  TRI_COMP(1)
  asm volatile("" ::: "memory");
  __builtin_amdgcn_s_barrier();

  short* staged = sm;
  #pragma unroll
  for (int m = 0; m < 4; ++m) {
    #pragma unroll
    for (int nn = 0; nn < 4; ++nn) {
      int cl = wc * 64 + nn * 16 + la;
      float ic = inv[col0 + cl];
      #pragma unroll
      for (int j = 0; j < 4; ++j) {
        int rl = wr * 64 + m * 16 + lb * 4 + j;
        staged[rl * 136 + cl] = f2b(__expf(acc[m][nn][j] * inv[row0 + rl] * ic));
      }
    }
  }
  __syncthreads();
  short* attb = att + (long)bat * 9437184L;
  float* rsb = rowsum + (long)bat * 3072;
  {
    int r = tid >> 1, half = tid & 1;
    short* dst = attb + (long)(row0 + r) * 3072 + col0 + half * 64;
    const short* src = &staged[r * 136 + half * 64];
    float s = 0.f;
    #pragma unroll
    for (int q = 0; q < 8; ++q) {
      bf16x8 v = *(const bf16x8*)&src[q * 8];
      *(bf16x8*)&dst[q * 8] = v;
      #pragma unroll
      for (int jj = 0; jj < 8; ++jj) s += b2f(v[jj]);
    }
    s += __shfl_xor(s, 1, 64);
    if (half == 0) atomicAdd(&rsb[row0 + r], s);
  }
  if (xt != yt) {
    int c = tid >> 1, half = tid & 1;
    short* dst = attb + (long)(col0 + c) * 3072 + row0 + half * 64;
    float s = 0.f;
    #pragma unroll
    for (int q = 0; q < 8; ++q) {
      bf16x8 o;
      #pragma unroll
      for (int jj = 0; jj < 8; ++jj) {
        o[jj] = staged[(half * 64 + q * 8 + jj) * 136 + c];
        s += b2f(o[jj]);
      }
      *(bf16x8*)&dst[q * 8] = o;
    }
    s += __shfl_xor(s, 1, 64);
    if (half == 0) atomicAdd(&rsb[col0 + c], s);
  }
}

// ---------------- merged af+sa GEMM1: raw f32 S, split-K atomics, BK=64 dbuf ----------
__global__ __launch_bounds__(256, 2) void gemm_s_all_k(
    const short* __restrict__ Aaf, const short* __restrict__ Asa,
    float* __restrict__ Sfaf, float* __restrict__ Sfsa)
{
  __shared__ short sm[32768];
  int bid = blockIdx.x;
  const short* A; float* Sf;
  int lda, ktotal, ksper, ldc, row0, col0, bat, kc;
  long sA, sS;
  if (bid < 288) {
    int txy = bid % 9, z = bid / 9;
    col0 = (txy % 3) * 128; row0 = (txy / 3) * 128;
    bat = z / 8; kc = z % 8;
    lda = 11520; ktotal = 180; ksper = 23; ldc = 384;
    sA = 4423680L; sS = 147456L; A = Aaf; Sf = Sfaf;
  } else {
    int id = bid - 288;
    int txy = id % 4, z = id / 4;
    col0 = (txy % 2) * 128; row0 = (txy / 2) * 128;
    bat = z / 16; kc = z % 16;
    lda = 15360; ktotal = 240; ksper = 15; ldc = 256;
    sA = 3932160L; sS = 65536L; A = Asa; Sf = Sfsa;
  }
  int tid = threadIdx.x;
  int wave = tid >> 6, lane = tid & 63;
  int la = lane & 15, lb = lane >> 4;
  const short* Ab = A + (long)bat * sA;
  int kb = kc * ksper, ke = min(ktotal, kb + ksper);
  int L = ke - kb;
  f32x4 acc[4][4] = {};
  int wr = wave >> 1, wc = wave & 1;
  int rloc = tid >> 3, cbase = (tid & 7) * 8;
  int ldsoff = tid * 8;

  const short *pA[4], *pB[4];
  #pragma unroll
  for (int p = 0; p < 4; ++p) {
    int row = p * 32 + rloc;
    int sc = SWZ(row, cbase);
    pA[p] = Ab + (long)(row0 + row) * lda + sc;
    pB[p] = Ab + (long)(col0 + row) * lda + sc;
  }

  #define GS_STAGE(KT, BUF) { \
    short* Asb = sm + (BUF) * 16384; \
    short* Bsb = Asb + 8192; \
    _Pragma("unroll") \
    for (int p = 0; p < 4; ++p) { \
      gload16(pA[p] + (KT) * 64, (void*)(Asb + p * 2048 + ldsoff)); \
      gload16(pB[p] + (KT) * 64, (void*)(Bsb + p * 2048 + ldsoff)); \
    } }
  #define GS_COMP(BUF) { \
    const short* Asb = sm + (BUF) * 16384; \
    const short* Bsb = Asb + 8192; \
    _Pragma("unroll") \
    for (int kk = 0; kk < 64; kk += 32) { \
      bf16x8 av[4], bv[4]; \
      _Pragma("unroll") \
      for (int m = 0; m < 4; ++m) \
        av[m] = *(const bf16x8*)&Asb[(wr * 64 + m * 16 + la) * 64 + SWZ(la, kk + lb * 8)]; \
      _Pragma("unroll") \
      for (int nn = 0; nn < 4; ++nn) \
        bv[nn] = *(const bf16x8*)&Bsb[(wc * 64 + nn * 16 + la) * 64 + SWZ(la, kk + lb * 8)]; \
      _Pragma("unroll") \
      for (int m = 0; m < 4; ++m) \
        _Pragma("unroll") \
        for (int nn = 0; nn < 4; ++nn) \
          acc[m][nn] = __builtin_amdgcn_mfma_f32_16x16x32_bf16(av[m], bv[nn], acc[m][nn], 0, 0, 0); \
    } }

  GS_STAGE(kb, 0)
  for (int t = 0; t < L - 1; ++t) {
    GS_STAGE(kb + t + 1, (t + 1) & 1)
    asm volatile("s_waitcnt vmcnt(8)" ::: "memory");
    __builtin_amdgcn_s_barrier();
    GS_COMP(t & 1)
    asm volatile("" ::: "memory");
    __builtin_amdgcn_s_barrier();
  }
  asm volatile("s_waitcnt vmcnt(0)" ::: "memory");
  __builtin_amdgcn_s_barrier();
  GS_COMP((L - 1) & 1)

  float* Sb = Sf + (long)bat * sS;
  #pragma unroll
  for (int m = 0; m < 4; ++m) {
    int gr0 = row0 + wr * 64 + m * 16 + lb * 4;
    #pragma unroll
    for (int nn = 0; nn < 4; ++nn) {
      int gc = col0 + wc * 64 + nn * 16 + la;
      #pragma unroll
      for (int j = 0; j < 4; ++j)
        atomicAdd(&Sb[(long)(gr0 + j) * ldc + gc], acc[m][nn][j]);
    }
  }
}

// ---------------- merged af+sa softmax: row-per-wave, in-register ----------------
__global__ __launch_bounds__(256) void softmax_all_k(
    const float* __restrict__ Sfaf, const float* __restrict__ Sfsa,
    const float* __restrict__ ssaf, const float* __restrict__ sssa,
    short* __restrict__ attaf, short* __restrict__ attsa)
{
  int wave = threadIdx.x >> 6, lane = threadIdx.x & 63;
  int rid = blockIdx.x * 4 + wave;
  int row, b, Mv, Mp; const float *Sf, *ss; short* att;
  if (rid < 1280) { row = rid % 320; b = rid / 320; Mv = 320; Mp = 384; Sf = Sfaf; ss = ssaf; att = attaf; }
  else { int id = rid - 1280; row = id % 240; b = id / 240; Mv = 240; Mp = 256; Sf = Sfsa; ss = sssa; att = attsa; }
  long sS = (long)Mp * Mp;
  const float* Sr = Sf + (long)b * sS + (long)row * Mp;
  const float* ssb = ss + b * Mp;
  float inv_i = rsqrtf(fmaxf(ssb[row], 1e-24f));
  float ev[6] = {0.f, 0.f, 0.f, 0.f, 0.f, 0.f};
  float sum = 0.f;
  #pragma unroll
  for (int q = 0; q < 6; ++q) {
    int j = q * 64 + lane;
    if (j < Mv) {
      float e = __expf(Sr[j] * inv_i * rsqrtf(fmaxf(ssb[j], 1e-24f)));
      ev[q] = e; sum += e;
    }
  }
  #pragma unroll
  for (int o = 32; o >= 1; o >>= 1) sum += __shfl_xor(sum, o, 64);
  float rden = 1.0f / sum;
  short* ar = att + (long)b * sS + (long)row * Mp;
  #pragma unroll
  for (int q = 0; q < 6; ++q) {
    int j = q * 64 + lane;
    if (j < Mp) ar[j] = (j < Mv) ? f2b(ev[q] * rden) : (short)0;
  }
}

// ---------------- sf GEMM2: 256x256 tile, 8 waves, 4-phase counted-vmcnt dbuf ----------
__global__ __launch_bounds__(512) void gemm2sf_k(const short* __restrict__ A,
                                                 const short* __restrict__ B,
                                                 const float* __restrict__ rowsum,
                                                 short* __restrict__ F) {
  __shared__ short sm[65536];
  int tid = threadIdx.x;
  int wave = tid >> 6, lane = tid & 63;
  int la = lane & 15, lb = lane >> 4;
  int wr = wave >> 2, wc = wave & 3;
  int wk;
  { int xcd = blockIdx.x & 7, j = blockIdx.x >> 3; wk = xcd * 30 + j; }
  int yt = wk % 12, rem = wk / 12;
  int xt = rem % 5, bat = rem / 5;
  const short* Ab = A + (long)bat * 9437184L;
  const short* Bb = B + (long)bat * 3932160L;
  int rloc = tid >> 3;
  int cbase = (tid & 7) * 8;
  int sc = cbase ^ ((rloc & 7) << 3);
  const short *pAg[4], *pBg[4];
  #pragma unroll
  for (int g = 0; g < 4; ++g) {
    pAg[g] = Ab + (long)(rloc * 48 + yt * 4 + g) * 3072 + sc;
    pBg[g] = Bb + (long)(xt * 256 + g * 64 + rloc) * 3072 + sc;
  }
  f32x4 acc[8][4] = {};

  #pragma unroll
  for (int g = 0; g < 4; ++g) {
    gload16(pAg[g], (void*)(sm + g * 4096 + tid * 8));
    gload16(pBg[g], (void*)(sm + 16384 + g * 4096 + tid * 8));
  }
  asm volatile("s_waitcnt vmcnt(0)" ::: "memory");
  __builtin_amdgcn_s_barrier();

  #define G2_PHASE(MH, KK, LOADB) { \
    if (LOADB) { \
      _Pragma("unroll") \
      for (int nn = 0; nn < 4; ++nn) \
        bv[nn] = *(const bf16x8*)&Bsb[(wc * 64 + nn * 16 + la) * 64 + SWZ(la, (KK) + lb * 8)]; \
    } \
    _Pragma("unroll") \
    for (int m = 0; m < 4; ++m) \
      av[m] = *(const bf16x8*)&Asb[(wr * 128 + (MH) * 64 + m * 16 + la) * 64 + SWZ(la, (KK) + lb * 8)]; \
    __builtin_amdgcn_s_setprio(1); \
    _Pragma("unroll") \
    for (int m = 0; m < 4; ++m) \
      _Pragma("unroll") \
      for (int nn = 0; nn < 4; ++nn) \
        acc[(MH) * 4 + m][nn] = __builtin_amdgcn_mfma_f32_16x16x32_bf16(av[m], bv[nn], acc[(MH) * 4 + m][nn], 0, 0, 0); \
    __builtin_amdgcn_s_setprio(0); \
  }

  for (int t = 0; t < 48; ++t) {
    const short* Asb = sm + (t & 1) * 32768;
    const short* Bsb = Asb + 16384;
    short* An = sm + ((t + 1) & 1) * 32768;
    short* Bn = An + 16384;
    int k1 = (t + 1) * 64;
    bool pf = (t < 47);
    bf16x8 av[4], bv[4];

    asm volatile("s_waitcnt vmcnt(2)" ::: "memory");
    __builtin_amdgcn_s_barrier();
    if (pf) { gload16(pBg[0] + k1, (void*)(Bn + tid * 8));
              gload16(pBg[1] + k1, (void*)(Bn + 4096 + tid * 8)); }
    G2_PHASE(0, 0, 1)
    if (pf) asm volatile("s_waitcnt vmcnt(2)" ::: "memory");
    else    asm volatile("s_waitcnt vmcnt(0)" ::: "memory");
    __builtin_amdgcn_s_barrier();
    if (pf) { gload16(pBg[2] + k1, (void*)(Bn + 8192 + tid * 8));
              gload16(pBg[3] + k1, (void*)(Bn + 12288 + tid * 8)); }
    G2_PHASE(1, 0, 0)
    asm volatile("s_waitcnt vmcnt(4)" ::: "memory");
    __builtin_amdgcn_s_barrier();
    if (pf) { gload16(pAg[0] + k1, (void*)(An + tid * 8));
              gload16(pAg[2] + k1, (void*)(An + 8192 + tid * 8)); }
    G2_PHASE(0, 32, 1)
    asm volatile("s_waitcnt vmcnt(6)" ::: "memory");
    __builtin_amdgcn_s_barrier();
    if (pf) { gload16(pAg[1] + k1, (void*)(An + 4096 + tid * 8));
              gload16(pAg[3] + k1, (void*)(An + 12288 + tid * 8)); }
    G2_PHASE(1, 32, 0)
  }
  __syncthreads();

  const float* rsb = rowsum + (long)bat * 3072;
  float rs[8][4];
  #pragma unroll
  for (int m = 0; m < 8; ++m) {
    int sub = wr * 2 + (m >> 2);
    #pragma unroll
    for (int j = 0; j < 4; ++j) {
      int cc = (m & 3) * 16 + lb * 4 + j;
      rs[m][j] = 1.0f / rsb[cc * 48 + yt * 4 + sub];
    }
  }
  short* staged = sm;
  #pragma unroll
  for (int m = 0; m < 8; ++m) {
    int sub = wr * 2 + (m >> 2);
    #pragma unroll
    for (int nn = 0; nn < 4; ++nn) {
      int gcl = wc * 64 + nn * 16 + la;
      int chunk = gcl * 4 + sub;
      int key = (gcl & 7) << 3;
      short4 o;
      o.x = f2b(acc[m][nn][0] * rs[m][0]); o.y = f2b(acc[m][nn][1] * rs[m][1]);
      o.z = f2b(acc[m][nn][2] * rs[m][2]); o.w = f2b(acc[m][nn][3] * rs[m][3]);
      *(short4*)&staged[chunk * 64 + (((m & 3) * 16 + lb * 4) ^ key)] = o;
    }
  }
  __syncthreads();
  #pragma unroll
  for (int i = 0; i < 16; ++i) {
    int chunk = i * 64 + (tid >> 3);
    int part = tid & 7;
    int gcl = chunk >> 2, sub = chunk & 3;
    int key = (gcl & 7) << 3;
    bf16x8 v = *(const bf16x8*)&staged[chunk * 64 + ((part * 8) ^ key)];
    int gc = xt * 256 + gcl;
    if (gc < 1200) {
      int hh = yt * 4 + sub;
      int wv = gc / 25, nidx = gc - wv * 25;
      long base = (((long)(bat * 48 + hh) * 48 + wv) * 25 + nidx) * 192 + part * 8;
      *(bf16x8*)&F[base] = v;
    }
  }
}

// ---------------- merged af+sa GEMM2 (1-phase) with XCD swizzle ----------------
__global__ __launch_bounds__(256) void gemm2_afsa_k(
    const short* __restrict__ attaf, const short* __restrict__ QTaf,
    const short* __restrict__ attsa, const short* __restrict__ QTsa,
    short* __restrict__ F)
{
  __shared__ short sm[20480];
  short* As = sm;
  short* Bs = sm + 4096;
  int bid = blockIdx.x;
  int isAF = (bid < 900);
  int NX, NY, LDA, KST, wk;
  const short *A, *B; long SA, SB;
  if (isAF) {
    NX = 45; NY = 5; LDA = 384; KST = 6; SA = 147456L; SB = 4423680L; A = attaf; B = QTaf;
    int xcd = bid & 7, j = bid >> 3;
    wk = (xcd < 4) ? xcd * 113 + j : 4 * 113 + (xcd - 4) * 112 + j;
  } else {
    NX = 60; NY = 4; LDA = 256; KST = 4; SA = 65536L; SB = 3932160L; A = attsa; B = QTsa;
    int id = bid - 900;
    int xcd = id & 7, j = id >> 3;
    wk = xcd * 120 + j;
  }
  int yt = wk % NY, rem = wk / NY;
  int xt = rem % NX, bat = rem / NX;
  int tid = threadIdx.x, wave = tid >> 6, lane = tid & 63;
  int la = lane & 15, lb = lane >> 4;
  const short* Ab = A + (long)bat * SA;
  const short* Bb = B + (long)bat * SB;
  f32x4 acc[4][4] = {};
  int rloc = tid >> 3, cbase = (tid & 7) * 8;
  int ldsoff = tid * 8;

  const short *pA[2], *pB[8];
  #pragma unroll
  for (int p = 0; p < 2; ++p) {
    int r = p * 32 + rloc;
    int sc = SWZ(r, cbase);
    int rowg = isAF ? (r * 5 + yt) : (yt * 64 + r);
    pA[p] = Ab + (long)rowg * LDA + sc;
  }
  #pragma unroll
  for (int p = 0; p < 8; ++p) {
    int rb = p * 32 + rloc;
    int sc = SWZ(rb, cbase);
    int rowg;
    if (isAF) rowg = xt * 256 + rb;
    else { int c = rb & 63, g = rb >> 6; rowg = c * 240 + xt * 4 + g; }
    pB[p] = Bb + (long)rowg * LDA + sc;
  }

  for (int kt = 0; kt < KST; ++kt) {
    #pragma unroll
    for (int p = 0; p < 2; ++p)
      gload16(pA[p] + kt * 64, (void*)(As + p * 2048 + ldsoff));
    #pragma unroll
    for (int p = 0; p < 8; ++p)
      gload16(pB[p] + kt * 64, (void*)(Bs + p * 2048 + ldsoff));
    __syncthreads();
    #pragma unroll
    for (int kk = 0; kk < 64; kk += 32) {
      bf16x8 av[4], bv[4];
      #pragma unroll
      for (int m = 0; m < 4; ++m)
        av[m] = *(const bf16x8*)&As[(m * 16 + la) * 64 + SWZ(la, kk + lb * 8)];
      #pragma unroll
      for (int nn = 0; nn < 4; ++nn)
        bv[nn] = *(const bf16x8*)&Bs[(wave * 64 + nn * 16 + la) * 64 + SWZ(la, kk + lb * 8)];
      #pragma unroll
      for (int m = 0; m < 4; ++m)
        #pragma unroll
        for (int nn = 0; nn < 4; ++nn)
          acc[m][nn] = __builtin_amdgcn_mfma_f32_16x16x32_bf16(av[m], bv[nn], acc[m][nn], 0, 0, 0);
    }
    __syncthreads();
  }

  short* staged = sm;
  #pragma unroll
  for (int m = 0; m < 4; ++m) {
    #pragma unroll
    for (int nn = 0; nn < 4; ++nn) {
      if (!isAF) {
        #pragma unroll
        for (int j = 0; j < 4; ++j)
          staged[((m * 16 + lb * 4 + j) * 4 + wave) * 72 + nn * 16 + la] = f2b(acc[m][nn][j]);
      } else {
        short4 o;
        o.x = f2b(acc[m][nn][0]); o.y = f2b(acc[m][nn][1]);
        o.z = f2b(acc[m][nn][2]); o.w = f2b(acc[m][nn][3]);
        *(short4*)&staged[(wave * 64 + nn * 16 + la) * 72 + m * 16 + lb * 4] = o;
      }
    }
  }
  __syncthreads();

  #pragma unroll
  for (int rd = 0; rd < 8; ++rd) {
    int chunk = rd * 32 + (tid >> 3);
    int part = tid & 7;
    bf16x8 v = *(const bf16x8*)&staged[chunk * 72 + part * 8];
    long base; bool ok = true;
    if (isAF) {
      int gc = xt * 256 + chunk;
      int hh = gc / 240, r2 = gc - hh * 240, v5 = r2 / 48, wv = r2 - v5 * 48;
      base = (((long)(bat * 48 + hh) * 48 + wv) * 25 + yt * 5 + v5) * 192 + 64 + part * 8;
    } else {
      int r = chunk >> 2, g = chunk & 3;
      int gr = yt * 64 + r; ok = (gr < 240);
      int hh = gr / 5, u = gr - hh * 5;
      int r2 = xt * 4 + g, v5 = r2 / 48, wv = r2 - v5 * 48;
      base = (((long)(bat * 48 + hh) * 48 + wv) * 25 + u * 5 + v5) * 192 + 128 + part * 8;
    }
    if (ok) *(bf16x8*)&F[base] = v;
  }
}

// ---------------- weight prep ----------------
__global__ __launch_bounds__(256) void prep_w_k(const float* __restrict__ w1, const float* __restrict__ w2,
                                                short* __restrict__ w1t, short* __restrict__ w2t) {
  int idx = blockIdx.x * 256 + threadIdx.x;
  if (idx < 12288) {
    int i = idx / 64, j = idx - i * 64;
    w1t[j * 192 + i] = f2b(w1[idx]);
  } else if (idx < 16384) {
    int k = idx - 12288;
    int i = k / 64, j = k - i * 64;
    w2t[j * 64 + i] = f2b(w2[k]);
  }
}

// ---------------- fused (+x) LayerNorm + MFMA MLP + residual ----------------
__global__ __launch_bounds__(256) void ln_mlp_mfma_k(
    const short* __restrict__ F, const float* __restrict__ x,
    const float* __restrict__ gamma, const float* __restrict__ beta,
    const short* __restrict__ w1t, const short* __restrict__ w2t,
    float* __restrict__ out)
{
  int n = blockIdx.x, hh = blockIdx.y, b = blockIdx.z;
  __shared__ short A1[48 * 200];
  __shared__ float xs[64 * 49];
  __shared__ __align__(16) char pool[19584];
  short* Fs = (short*)pool;
  short* Y1 = (short*)pool;
  float* Y2 = (float*)(pool + 6912);
  int tid = threadIdx.x, wave = tid >> 6, lane = tid & 63;
  int la = lane & 15, lb = lane >> 4;
  long Fb0 = ((long)(b * 48 + hh) * 1200 + n) * 192;
  long xb = (long)b * 3686400 + (long)n * 2304 + hh * 48;

  #pragma unroll
  for (int it = 0; it < 5; ++it) {
    int ci = tid + 256 * it;
    if (ci < 1152) {
      int r = ci / 24, q = ci - r * 24;
      gload16(&F[Fb0 + (long)r * 4800 + q * 8], (void*)(Fs + ci * 8));
    }
  }
  {
    int ch = tid >> 2, qq = tid & 3;
    const float* xr = x + xb + (long)ch * 57600 + qq * 12;
    #pragma unroll
    for (int i = 0; i < 12; ++i) xs[ch * 49 + qq * 12 + i] = xr[i];
  }
  __syncthreads();

  float g0 = gamma[lane], g1 = gamma[lane + 64], g2 = gamma[lane + 128];
  float bt0 = beta[lane], bt1 = beta[lane + 64], bt2 = beta[lane + 128];
  #pragma unroll 4
  for (int rr = 0; rr < 12; ++rr) {
    int r = wave * 12 + rr;
    float xv = xs[lane * 49 + r];
    float v0 = b2f(Fs[r * 192 + lane]) + xv;
    float v1 = b2f(Fs[r * 192 + lane + 64]) + xv;
    float v2 = b2f(Fs[r * 192 + lane + 128]) + xv;
    float s = v0 + v1 + v2;
    #pragma unroll
    for (int o = 32; o >= 1; o >>= 1) s += __shfl_xor(s, o, 64);
    float mu = s * (1.f / 192.f);
    float d0 = v0 - mu, d1 = v1 - mu, d2 = v2 - mu;
    float q = d0 * d0 + d1 * d1 + d2 * d2;
    #pragma unroll
    for (int o = 32; o >= 1; o >>= 1) q += __shfl_xor(q, o, 64);
    float rsq = rsqrtf(q * (1.f / 192.f) + 1e-5f);
    A1[r * 200 + lane]       = f2b(d0 * rsq * g0 + bt0);
    A1[r * 200 + lane + 64]  = f2b(d1 * rsq * g1 + bt1);
    A1[r * 200 + lane + 128] = f2b(d2 * rsq * g2 + bt2);
  }
  __syncthreads();

  f32x4 acc1[3] = {};
  #pragma unroll
  for (int ks = 0; ks < 6; ++ks) {
    bf16x8 bv = *(const bf16x8*)&w1t[(wave * 16 + la) * 192 + ks * 32 + lb * 8];
    #pragma unroll
    for (int m = 0; m < 3; ++m) {
      bf16x8 av = *(const bf16x8*)&A1[(m * 16 + la) * 200 + ks * 32 + lb * 8];
      acc1[m] = __builtin_amdgcn_mfma_f32_16x16x32_bf16(av, bv, acc1[m], 0, 0, 0);
    }
  }
  #pragma unroll
  for (int m = 0; m < 3; ++m)
    #pragma unroll
    for (int j = 0; j < 4; ++j)
      Y1[(m * 16 + lb * 4 + j) * 72 + wave * 16 + la] = f2b(fmaxf(acc1[m][j], 0.f));
  __syncthreads();

  f32x4 acc2[3] = {};
  #pragma unroll
  for (int ks = 0; ks < 2; ++ks) {
    bf16x8 bv = *(const bf16x8*)&w2t[(wave * 16 + la) * 64 + ks * 32 + lb * 8];
    #pragma unroll
    for (int m = 0; m < 3; ++m) {
      bf16x8 av = *(const bf16x8*)&Y1[(m * 16 + la) * 72 + ks * 32 + lb * 8];
      acc2[m] = __builtin_amdgcn_mfma_f32_16x16x32_bf16(av, bv, acc2[m], 0, 0, 0);
    }
  }
  #pragma unroll
  for (int m = 0; m < 3; ++m)
    #pragma unroll
    for (int j = 0; j < 4; ++j)
      Y2[(m * 16 + lb * 4 + j) * 66 + wave * 16 + la] = acc2[m][j];
  __syncthreads();

  #pragma unroll
  for (int i = 0; i < 12; ++i) {
    int e = tid + 256 * i;
    int cc = e / 48, wv = e - cc * 48;
    out[xb + (long)cc * 57600 + wv] = Y2[wv * 66 + cc] + xs[cc * 49 + wv];
  }
}

// ---------------- host launcher ----------------
extern "C" void kernel_launch(void* const* d_in, const int* in_sizes, int n_in,
                              void* d_out, int out_size, void* d_ws, size_t ws_size,
                              hipStream_t stream) {
  (void)in_sizes; (void)n_in; (void)out_size;
  const float* x     = (const float*)d_in[0];
  const float* gamma = (const float*)d_in[1];
  const float* beta  = (const float*)d_in[2];
  const float* w1    = (const float*)d_in[3];
  const float* w2    = (const float*)d_in[4];
  float* out = (float*)d_out;

  const size_t NEED = 237191168UL;
  if (ws_size < NEED) return;
  char* ws = (char*)d_ws;
  short* F     = (short*)(ws);
  short* attsf = (short*)(ws + 88473600UL);
  short* Qsf   = (short*)(ws + 163971072UL);
  short* QTsf  = (short*)(ws + 199360512UL);
  float* rowsum = (float*)(ws + 234749952UL);
  float* invn  = (float*)(ws + 237109248UL);
  short* w1t   = (short*)(ws + 237158400UL);
  short* w2t   = (short*)(ws + 237182976UL);
  // phase 2 (af+sa) reuses sf regions
  short* Qaf   = (short*)(ws + 88473600UL);
  short* QTaf  = (short*)(ws + 123863040UL);
  float* Sfsa  = (float*)(ws + 159252480UL);
  float* ssaf  = (float*)(ws + 160301056UL);
  float* sssa  = (float*)(ws + 160307200UL);
  short* attaf = (short*)(ws + 160311296UL);
  short* attsa = (short*)(ws + 161490944UL);
  short* Qsa   = (short*)(ws + 163971072UL);
  short* QTsa  = (short*)(ws + 195428352UL);
  float* Sfaf  = (float*)(ws + 234749952UL);

  prep_w_k<<<64, 256, 0, stream>>>(w1, w2, w1t, w2t);

  // ================= SF =================
  permute_sf_k<<<3072, 256, 0, stream>>>(x, Qsf, invn);
  transpose_k<<<dim3(40, 96, 4), 256, 0, stream>>>(Qsf, QTsf, 3072, 1280);
  hipMemsetAsync(rowsum, 0, 49152, stream);
  gemm1_tri_k<<<dim3(300, 1, 4), 256, 0, stream>>>(Qsf, invn, attsf, rowsum);
  gemm2sf_k<<<dim3(240), 512, 0, stream>>>(attsf, QTsf, rowsum, F);

  // ================= AF + SA merged =================
  hipMemsetAsync(Sfaf, 0, 2359296, stream);
  hipMemsetAsync((char*)Sfsa, 0, 1058816, stream);   // Sfsa + ssaf + sssa (contiguous)
  permtr_all_k<<<32640, 256, 0, stream>>>(x, Qaf, QTaf, Qsa, QTsa, ssaf, sssa);
  gemm_s_all_k<<<544, 256, 0, stream>>>(Qaf, Qsa, Sfaf, Sfsa);
  softmax_all_k<<<560, 256, 0, stream>>>(Sfaf, Sfsa, ssaf, sssa, attaf, attsa);
  gemm2_afsa_k<<<1860, 256, 0, stream>>>(attaf, QTaf, attsa, QTsa, F);

  // ================= LN + MLP + residual =================
  ln_mlp_mfma_k<<<dim3(25, 48, 4), 256, 0, stream>>>(F, x, gamma, beta, w1t, w2t, out);
}